// Round 1
// baseline (4754.333 us; speedup 1.0000x reference)
//
#include <hip/hip_runtime.h>
#include <cmath>

#define BATCH 2
#define CIN 3
#define HH 96
#define WW 96
#define NSP (HH*WW)      // 9216
#define CHN 64
#define C8 8
#define NBLK 5

// ---------------------------------------------------------------------------
// conv 9x9 (3 -> 64), pad 4, + PReLU(scalar slope)
__global__ __launch_bounds__(256) void k_conv_in(const float* __restrict__ x,
        const float* __restrict__ w, const float* __restrict__ bias,
        const float* __restrict__ a, float* __restrict__ out) {
    int idx = blockIdx.x * 256 + threadIdx.x;
    if (idx >= BATCH*CHN*NSP) return;
    int n  = idx % NSP;
    int co = (idx / NSP) % CHN;
    int b  = idx / (NSP*CHN);
    int y = n / WW, xx = n % WW;
    float sum = bias[co];
    int ky0 = max(0, 4 - y),  ky1 = min(9, 100 - y);
    int kx0 = max(0, 4 - xx), kx1 = min(9, 100 - xx);
    for (int ci = 0; ci < CIN; ++ci) {
        const float* xin = x + ((size_t)(b*CIN + ci))*NSP;
        const float* wp  = w + ((size_t)(co*CIN + ci))*81;
        for (int ky = ky0; ky < ky1; ++ky) {
            const float* row = xin + (y + ky - 4)*WW + (xx - 4);
            const float* wr  = wp + ky*9;
            for (int kx = kx0; kx < kx1; ++kx)
                sum = fmaf(row[kx], wr[kx], sum);
        }
    }
    float sl = a[0];
    out[idx] = sum >= 0.f ? sum : sl*sum;
}

// ---------------------------------------------------------------------------
// conv 3x3 (64 -> 64), pad 1, + PReLU(scalar slope)
__global__ __launch_bounds__(256) void k_conv3_prelu(const float* __restrict__ in,
        const float* __restrict__ w, const float* __restrict__ bias,
        const float* __restrict__ a, float* __restrict__ out) {
    int idx = blockIdx.x * 256 + threadIdx.x;
    if (idx >= BATCH*CHN*NSP) return;
    int n  = idx % NSP;
    int co = (idx / NSP) % CHN;
    int b  = idx / (NSP*CHN);
    int y = n / WW, xx = n % WW;
    float sum = bias[co];
    int ky0 = max(0, 1 - y),  ky1 = min(3, 97 - y);
    int kx0 = max(0, 1 - xx), kx1 = min(3, 97 - xx);
    const float* inb = in + ((size_t)b)*CHN*NSP;
    const float* wb  = w + ((size_t)co)*CHN*9;
    for (int ci = 0; ci < CHN; ++ci) {
        const float* xin = inb + ci*NSP;
        const float* wp  = wb + ci*9;
        for (int ky = ky0; ky < ky1; ++ky) {
            const float* row = xin + (y + ky - 1)*WW + (xx - 1);
            const float* wr  = wp + ky*3;
            for (int kx = kx0; kx < kx1; ++kx)
                sum = fmaf(row[kx], wr[kx], sum);
        }
    }
    float sl = a[0];
    out[idx] = sum >= 0.f ? sum : sl*sum;
}

// conv 3x3 (64 -> 64), pad 1, + bias + residual add.  res/out may alias (same idx only).
__global__ __launch_bounds__(256) void k_conv3_add(const float* __restrict__ in,
        const float* __restrict__ w, const float* __restrict__ bias,
        const float* res, float* out) {
    int idx = blockIdx.x * 256 + threadIdx.x;
    if (idx >= BATCH*CHN*NSP) return;
    int n  = idx % NSP;
    int co = (idx / NSP) % CHN;
    int b  = idx / (NSP*CHN);
    int y = n / WW, xx = n % WW;
    float sum = bias[co];
    int ky0 = max(0, 1 - y),  ky1 = min(3, 97 - y);
    int kx0 = max(0, 1 - xx), kx1 = min(3, 97 - xx);
    const float* inb = in + ((size_t)b)*CHN*NSP;
    const float* wb  = w + ((size_t)co)*CHN*9;
    for (int ci = 0; ci < CHN; ++ci) {
        const float* xin = inb + ci*NSP;
        const float* wp  = wb + ci*9;
        for (int ky = ky0; ky < ky1; ++ky) {
            const float* row = xin + (y + ky - 1)*WW + (xx - 1);
            const float* wr  = wp + ky*3;
            for (int kx = kx0; kx < kx1; ++kx)
                sum = fmaf(row[kx], wr[kx], sum);
        }
    }
    out[idx] = sum + res[idx];
}

// ---------------------------------------------------------------------------
// 1x1 projections: Q[B,8,N], K[B,8,N], V^T[B,N,64]
__global__ __launch_bounds__(256) void k_qkv(const float* __restrict__ f,
        const float* __restrict__ wq, const float* __restrict__ bq,
        const float* __restrict__ wk, const float* __restrict__ bk,
        const float* __restrict__ wv, const float* __restrict__ bv,
        float* __restrict__ Qo, float* __restrict__ Ko, float* __restrict__ VT) {
    int idx = blockIdx.x * 256 + threadIdx.x;   // b*NSP + n
    if (idx >= BATCH*NSP) return;
    int b = idx / NSP, n = idx % NSP;
    float xv[CHN];
    #pragma unroll
    for (int c = 0; c < CHN; ++c)
        xv[c] = f[((size_t)(b*CHN + c))*NSP + n];
    #pragma unroll
    for (int o = 0; o < C8; ++o) {
        float q = bq[o], k = bk[o];
        #pragma unroll
        for (int c = 0; c < CHN; ++c) {
            q = fmaf(wq[o*CHN + c], xv[c], q);
            k = fmaf(wk[o*CHN + c], xv[c], k);
        }
        Qo[((size_t)(b*C8 + o))*NSP + n] = q;
        Ko[((size_t)(b*C8 + o))*NSP + n] = k;
    }
    for (int o = 0; o < CHN; ++o) {
        float v = bv[o];
        #pragma unroll
        for (int c = 0; c < CHN; ++c)
            v = fmaf(wv[o*CHN + c], xv[c], v);
        VT[(((size_t)b)*NSP + n)*CHN + o] = v;
    }
}

// ---------------------------------------------------------------------------
// flash-style attention: 16 query rows per block, online softmax over j-chunks
// of 256.  out[b,c,i] = gamma * (sum_j p_ij v[c,j]) / l_i + F[b,c,i]
__global__ __launch_bounds__(256) void k_attn(const float* __restrict__ Qi,
        const float* __restrict__ Ki, const float* __restrict__ VT,
        const float* __restrict__ F, const float* __restrict__ gamma_p,
        float* __restrict__ out) {
    __shared__ float q_lds[16][8];
    __shared__ float p_lds[256][16];
    __shared__ float red[4][16];
    __shared__ float m_lds[16], l_lds[16], alpha_lds[16];

    int blk = blockIdx.x;
    int b   = blk / (NSP/16);
    int i0  = (blk % (NSP/16)) * 16;
    int t    = threadIdx.x;
    int lane = t & 63;
    int wave = t >> 6;
    int c  = t & 63;        // output channel for PV phase
    int rg = t >> 6;        // row group: rows rg*4 .. rg*4+3

    if (t < 128) {
        int r = t >> 3, o = t & 7;
        q_lds[r][o] = Qi[((size_t)(b*C8 + o))*NSP + i0 + r];
    }
    if (t < 16) { m_lds[t] = -1e30f; l_lds[t] = 0.f; }
    float acc0 = 0.f, acc1 = 0.f, acc2 = 0.f, acc3 = 0.f;
    __syncthreads();

    for (int j0 = 0; j0 < NSP; j0 += 256) {
        int j = j0 + t;
        float kv[8];
        #pragma unroll
        for (int o = 0; o < 8; ++o)
            kv[o] = Ki[((size_t)(b*C8 + o))*NSP + j];
        float e[16];
        #pragma unroll
        for (int r = 0; r < 16; ++r) {
            float4 qa = *(const float4*)&q_lds[r][0];
            float4 qb = *(const float4*)&q_lds[r][4];
            e[r] = qa.x*kv[0] + qa.y*kv[1] + qa.z*kv[2] + qa.w*kv[3]
                 + qb.x*kv[4] + qb.y*kv[5] + qb.z*kv[6] + qb.w*kv[7];
        }
        // per-row max across the 256 threads of the chunk
        #pragma unroll
        for (int r = 0; r < 16; ++r) {
            float v = e[r];
            for (int off = 32; off > 0; off >>= 1)
                v = fmaxf(v, __shfl_xor(v, off));
            if (lane == 0) red[wave][r] = v;
        }
        __syncthreads();
        if (t < 16) {
            float cm = fmaxf(fmaxf(red[0][t], red[1][t]), fmaxf(red[2][t], red[3][t]));
            float m_old = m_lds[t];
            float m_new = fmaxf(m_old, cm);
            m_lds[t] = m_new;
            alpha_lds[t] = __expf(m_old - m_new);   // exp(-1e30)=0 on first chunk
        }
        __syncthreads();
        // p = exp(e - m_new), per-row chunk sums
        #pragma unroll
        for (int r = 0; r < 16; ++r) {
            float p = __expf(e[r] - m_lds[r]);
            e[r] = p;
            float s = p;
            for (int off = 32; off > 0; off >>= 1)
                s += __shfl_xor(s, off);
            if (lane == 0) red[wave][r] = s;
        }
        *(float4*)&p_lds[t][0]  = make_float4(e[0],  e[1],  e[2],  e[3]);
        *(float4*)&p_lds[t][4]  = make_float4(e[4],  e[5],  e[6],  e[7]);
        *(float4*)&p_lds[t][8]  = make_float4(e[8],  e[9],  e[10], e[11]);
        *(float4*)&p_lds[t][12] = make_float4(e[12], e[13], e[14], e[15]);
        __syncthreads();
        if (t < 16)
            l_lds[t] = l_lds[t]*alpha_lds[t]
                     + (red[0][t] + red[1][t] + red[2][t] + red[3][t]);
        // PV phase: thread (rg, c) accumulates rows rg*4..rg*4+3, channel c
        float al0 = alpha_lds[rg*4 + 0];
        float al1 = alpha_lds[rg*4 + 1];
        float al2 = alpha_lds[rg*4 + 2];
        float al3 = alpha_lds[rg*4 + 3];
        acc0 *= al0; acc1 *= al1; acc2 *= al2; acc3 *= al3;
        const float* vt = VT + (((size_t)b)*NSP + j0)*CHN + c;
        for (int jj = 0; jj < 256; ++jj) {
            float vv = vt[(size_t)jj*CHN];
            float4 p4 = *(const float4*)&p_lds[jj][rg*4];
            acc0 = fmaf(p4.x, vv, acc0);
            acc1 = fmaf(p4.y, vv, acc1);
            acc2 = fmaf(p4.z, vv, acc2);
            acc3 = fmaf(p4.w, vv, acc3);
        }
        __syncthreads();
    }
    float g = gamma_p[0];
    float li0 = 1.f / l_lds[rg*4 + 0];
    float li1 = 1.f / l_lds[rg*4 + 1];
    float li2 = 1.f / l_lds[rg*4 + 2];
    float li3 = 1.f / l_lds[rg*4 + 3];
    size_t base = ((size_t)(b*CHN + c))*NSP + i0;
    out[base + rg*4 + 0] = g*(acc0*li0) + F[base + rg*4 + 0];
    out[base + rg*4 + 1] = g*(acc1*li1) + F[base + rg*4 + 1];
    out[base + rg*4 + 2] = g*(acc2*li2) + F[base + rg*4 + 2];
    out[base + rg*4 + 3] = g*(acc3*li3) + F[base + rg*4 + 3];
}

// ---------------------------------------------------------------------------
// conv 9x9 (64 -> 3), pad 4, + tanh
__global__ __launch_bounds__(256) void k_conv_out(const float* __restrict__ in,
        const float* __restrict__ w, const float* __restrict__ bias,
        float* __restrict__ out) {
    int idx = blockIdx.x * 256 + threadIdx.x;
    if (idx >= BATCH*CIN*NSP) return;
    int n  = idx % NSP;
    int co = (idx / NSP) % CIN;
    int b  = idx / (NSP*CIN);
    int y = n / WW, xx = n % WW;
    float sum = bias[co];
    int ky0 = max(0, 4 - y),  ky1 = min(9, 100 - y);
    int kx0 = max(0, 4 - xx), kx1 = min(9, 100 - xx);
    for (int ci = 0; ci < CHN; ++ci) {
        const float* xin = in + ((size_t)(b*CHN + ci))*NSP;
        const float* wp  = w + ((size_t)(co*CHN + ci))*81;
        for (int ky = ky0; ky < ky1; ++ky) {
            const float* row = xin + (y + ky - 4)*WW + (xx - 4);
            const float* wr  = wp + ky*9;
            for (int kx = kx0; kx < kx1; ++kx)
                sum = fmaf(row[kx], wr[kx], sum);
        }
    }
    out[idx] = tanhf(sum);
}

// ---------------------------------------------------------------------------
extern "C" void kernel_launch(void* const* d_in, const int* in_sizes, int n_in,
                              void* d_out, int out_size, void* d_ws, size_t ws_size,
                              hipStream_t stream) {
    (void)in_sizes; (void)n_in; (void)out_size; (void)ws_size;
    const float* x     = (const float*)d_in[0];
    const float* w_in  = (const float*)d_in[1];
    const float* b_in  = (const float*)d_in[2];
    const float* a_in  = (const float*)d_in[3];
    const float* rw1   = (const float*)d_in[4];
    const float* rb1   = (const float*)d_in[5];
    const float* ra    = (const float*)d_in[6];
    const float* rw2   = (const float*)d_in[7];
    const float* rb2   = (const float*)d_in[8];
    const float* wq    = (const float*)d_in[9];
    const float* bq    = (const float*)d_in[10];
    const float* wk    = (const float*)d_in[11];
    const float* bk    = (const float*)d_in[12];
    const float* wv    = (const float*)d_in[13];
    const float* bv    = (const float*)d_in[14];
    const float* gamma = (const float*)d_in[15];
    const float* w_out = (const float*)d_in[16];
    const float* b_out = (const float*)d_in[17];

    // workspace layout (floats):
    //   A  : [B,64,N] feature buffer        1179648
    //   Bf : [B,64,N] feature buffer        1179648
    //   Qb : [B,8,N]                         147456
    //   Kb : [B,8,N]                         147456
    //   VT : [B,N,64]                       1179648
    float* A  = (float*)d_ws;
    float* Bf = A  + (size_t)BATCH*CHN*NSP;
    float* Qb = Bf + (size_t)BATCH*CHN*NSP;
    float* Kb = Qb + (size_t)BATCH*C8*NSP;
    float* VT = Kb + (size_t)BATCH*C8*NSP;
    float* outp = (float*)d_out;

    const int feat = BATCH*CHN*NSP;          // 1179648
    dim3 blk(256);

    k_conv_in<<<(feat + 255)/256, blk, 0, stream>>>(x, w_in, b_in, a_in, A);
    for (int i = 0; i < NBLK; ++i) {
        k_conv3_prelu<<<(feat + 255)/256, blk, 0, stream>>>(
            A, rw1 + (size_t)i*CHN*CHN*9, rb1 + i*CHN, ra + i, Bf);
        k_conv3_add<<<(feat + 255)/256, blk, 0, stream>>>(
            Bf, rw2 + (size_t)i*CHN*CHN*9, rb2 + i*CHN, A, A);
    }
    k_qkv<<<(BATCH*NSP + 255)/256, blk, 0, stream>>>(
        A, wq, bq, wk, bk, wv, bv, Qb, Kb, VT);
    k_attn<<<BATCH*(NSP/16), blk, 0, stream>>>(Qb, Kb, VT, A, gamma, Bf);
    k_conv_out<<<(BATCH*CIN*NSP + 255)/256, blk, 0, stream>>>(Bf, w_out, b_out, outp);
}

// Round 3
// 2579.299 us; speedup vs baseline: 1.8433x; 1.8433x over previous
//
#include <hip/hip_runtime.h>
#include <cmath>

#define BATCH 2
#define CIN 3
#define HH 96
#define WW 96
#define NSP (HH*WW)      // 9216
#define CHN 64
#define C8 8
#define NBLK 5

#define PW 98            // padded width/height
#define PN (PW*PW)       // 9604 padded spatial
#define GUARD 128        // guard entries (spatial) each side of FB buffers
#define FBSTRIDE ((PN + 2*GUARD)*CHN)   // shorts per batch in FB buffers

typedef __attribute__((ext_vector_type(8))) short bf16x8;
typedef __attribute__((ext_vector_type(4))) float f32x4;

static __device__ __forceinline__ short f2b(float f) {
    union { float f; unsigned u; } v; v.f = f;
    unsigned r = (v.u + 0x7FFFu + ((v.u >> 16) & 1u)) >> 16;
    return (short)r;
}
static __device__ __forceinline__ float b2f(short s) {
    union { unsigned u; float f; } v; v.u = ((unsigned)(unsigned short)s) << 16;
    return v.f;
}
// split v into hi+lo bf16
static __device__ __forceinline__ void split2(float v, short& hi, short& lo) {
    hi = f2b(v);
    lo = f2b(v - b2f(hi));
}

// ---------------------------------------------------------------------------
// weight prep: rw[blk][co][ci][3][3] fp32 -> Whi/Wlo[conv][kyx][co][ci] bf16
__global__ __launch_bounds__(256) void k_prep_w(const float* __restrict__ rw1,
        const float* __restrict__ rw2, short* __restrict__ Whi,
        short* __restrict__ Wlo) {
    int idx = blockIdx.x * 256 + threadIdx.x;
    const int TOT = NBLK*2*9*CHN*CHN;
    if (idx >= TOT) return;
    int ci  = idx & 63;
    int co  = (idx >> 6) & 63;
    int kyx = (idx >> 12) % 9;
    int conv = idx / (9*CHN*CHN);
    int blk = conv >> 1, s = conv & 1;
    const float* src = s ? rw2 : rw1;
    float v = src[(((size_t)(blk*CHN + co))*CHN + ci)*9 + kyx];
    short h, l; split2(v, h, l);
    Whi[idx] = h; Wlo[idx] = l;
}

// ---------------------------------------------------------------------------
// conv 9x9 (3 -> 64), pad 4, + PReLU -> FR (fp32 n-major padded) + FBhi/FBlo
__global__ __launch_bounds__(256) void k_conv_in(const float* __restrict__ x,
        const float* __restrict__ w, const float* __restrict__ bias,
        const float* __restrict__ a, float* __restrict__ FR,
        short* __restrict__ FBhi, short* __restrict__ FBlo) {
    int idx = blockIdx.x * 256 + threadIdx.x;
    if (idx >= BATCH*CHN*NSP) return;
    int n  = idx % NSP;
    int co = (idx / NSP) % CHN;
    int b  = idx / (NSP*CHN);
    int y = n / WW, xx = n % WW;
    float sum = bias[co];
    int ky0 = max(0, 4 - y),  ky1 = min(9, 100 - y);
    int kx0 = max(0, 4 - xx), kx1 = min(9, 100 - xx);
    for (int ci = 0; ci < CIN; ++ci) {
        const float* xin = x + ((size_t)(b*CIN + ci))*NSP;
        const float* wp  = w + ((size_t)(co*CIN + ci))*81;
        for (int ky = ky0; ky < ky1; ++ky) {
            const float* row = xin + (y + ky - 4)*WW + (xx - 4);
            const float* wr  = wp + ky*9;
            for (int kx = kx0; kx < kx1; ++kx)
                sum = fmaf(row[kx], wr[kx], sum);
        }
    }
    float sl = a[0];
    float v = sum >= 0.f ? sum : sl*sum;
    int np = (y + 1)*PW + xx + 1;
    FR[((size_t)b*PN + np)*CHN + co] = v;
    short h, l; split2(v, h, l);
    FBhi[(size_t)b*FBSTRIDE + (size_t)np*CHN + co] = h;
    FBlo[(size_t)b*FBSTRIDE + (size_t)np*CHN + co] = l;
}

// ---------------------------------------------------------------------------
// 3x3 conv 64->64, implicit GEMM, split-bf16 3-MFMA (~fp32 precision).
// Block: 64 co x 64 spatial. 4 waves; wave w = sp-col w, 4 co-tiles.
// mode 0: out = prelu(conv+bias)          -> FBout hi/lo
// mode 1: v = conv+bias+FR; FR = v        -> FBout hi/lo
__global__ __launch_bounds__(256) void k_conv3_mfma(
        const short* __restrict__ FBhi_in, const short* __restrict__ FBlo_in,
        const short* __restrict__ Whi, const short* __restrict__ Wlo,
        const float* __restrict__ bias, const float* __restrict__ slope_p,
        float* __restrict__ FR,
        short* __restrict__ FBhi_out, short* __restrict__ FBlo_out, int mode) {
    int t = threadIdx.x;
    int w = t >> 6, lane = t & 63;
    int q = lane >> 4, n16 = lane & 15;
    int blk = blockIdx.x;
    int b = blk / 147, chunk = blk % 147;
    int nb = 98 + chunk*64 + w*16 + n16;        // this lane's padded spatial idx

    const short* fbh = FBhi_in + (size_t)b*FBSTRIDE;
    const short* fbl = FBlo_in + (size_t)b*FBSTRIDE;
    f32x4 acc[4] = {{0,0,0,0},{0,0,0,0},{0,0,0,0},{0,0,0,0}};

    int nbase = nb*CHN;
    #pragma unroll
    for (int kyx = 0; kyx < 9; ++kyx) {
        int dy = kyx/3 - 1, dx = kyx%3 - 1;
        int boff = nbase + (dy*PW + dx)*CHN;
        const short* wph = Whi + (size_t)kyx*CHN*CHN;
        const short* wpl = Wlo + (size_t)kyx*CHN*CHN;
        #pragma unroll
        for (int cih = 0; cih < 2; ++cih) {
            int xoff = boff + cih*32 + q*8;
            bf16x8 bhi = *(const bf16x8*)(fbh + xoff);
            bf16x8 blo = *(const bf16x8*)(fbl + xoff);
            #pragma unroll
            for (int ct = 0; ct < 4; ++ct) {
                int aoff = (ct*16 + n16)*CHN + cih*32 + q*8;
                bf16x8 ahi = *(const bf16x8*)(wph + aoff);
                bf16x8 alo = *(const bf16x8*)(wpl + aoff);
                acc[ct] = __builtin_amdgcn_mfma_f32_16x16x32_bf16(ahi, bhi, acc[ct], 0, 0, 0);
                acc[ct] = __builtin_amdgcn_mfma_f32_16x16x32_bf16(ahi, blo, acc[ct], 0, 0, 0);
                acc[ct] = __builtin_amdgcn_mfma_f32_16x16x32_bf16(alo, bhi, acc[ct], 0, 0, 0);
            }
        }
    }

    int yy = nb / PW;
    int xx = nb - yy*PW;
    if (xx < 1 || xx > 96 || yy < 1 || yy > 96) return;
    float sl = slope_p[0];
    short* fboh = FBhi_out + (size_t)b*FBSTRIDE + (size_t)nb*CHN;
    short* fbol = FBlo_out + (size_t)b*FBSTRIDE + (size_t)nb*CHN;
    float* fr  = FR + ((size_t)b*PN + nb)*CHN;
    #pragma unroll
    for (int ct = 0; ct < 4; ++ct) {
        #pragma unroll
        for (int r = 0; r < 4; ++r) {
            int co = ct*16 + q*4 + r;
            float v = acc[ct][r] + bias[co];
            if (mode == 0) {
                v = v >= 0.f ? v : sl*v;
            } else {
                v += fr[co];
                fr[co] = v;
            }
            short h, l; split2(v, h, l);
            fboh[co] = h;
            fbol[co] = l;
        }
    }
}

// ---------------------------------------------------------------------------
// 1x1 projections from FR (n-major): Q[B,8,N], K[B,8,N], V^T[B,N,64]
__global__ __launch_bounds__(256) void k_qkv(const float* __restrict__ FR,
        const float* __restrict__ wq, const float* __restrict__ bq,
        const float* __restrict__ wk, const float* __restrict__ bk,
        const float* __restrict__ wv, const float* __restrict__ bv,
        float* __restrict__ Qo, float* __restrict__ Ko, float* __restrict__ VT) {
    int idx = blockIdx.x * 256 + threadIdx.x;   // b*NSP + n
    if (idx >= BATCH*NSP) return;
    int b = idx / NSP, n = idx % NSP;
    int y = n / WW, xx = n % WW;
    int np = (y + 1)*PW + xx + 1;
    const float* xp = FR + ((size_t)b*PN + np)*CHN;
    float xv[CHN];
    #pragma unroll
    for (int c = 0; c < CHN; c += 4) {
        float4 f4 = *(const float4*)(xp + c);
        xv[c] = f4.x; xv[c+1] = f4.y; xv[c+2] = f4.z; xv[c+3] = f4.w;
    }
    #pragma unroll
    for (int o = 0; o < C8; ++o) {
        float qv = bq[o], kv = bk[o];
        #pragma unroll
        for (int c = 0; c < CHN; ++c) {
            qv = fmaf(wq[o*CHN + c], xv[c], qv);
            kv = fmaf(wk[o*CHN + c], xv[c], kv);
        }
        Qo[((size_t)(b*C8 + o))*NSP + n] = qv;
        Ko[((size_t)(b*C8 + o))*NSP + n] = kv;
    }
    for (int o = 0; o < CHN; ++o) {
        float v = bv[o];
        #pragma unroll
        for (int c = 0; c < CHN; ++c)
            v = fmaf(wv[o*CHN + c], xv[c], v);
        VT[(((size_t)b)*NSP + n)*CHN + o] = v;
    }
}

// ---------------------------------------------------------------------------
// flash-style attention; p_lds padded to stride 20 (8-way instead of 32-way
// write conflicts, b128 broadcast reads stay 16B-aligned)
__global__ __launch_bounds__(256) void k_attn(const float* __restrict__ Qi,
        const float* __restrict__ Ki, const float* __restrict__ VT,
        const float* __restrict__ FR, const float* __restrict__ gamma_p,
        float* __restrict__ out) {
    __shared__ float q_lds[16][8];
    __shared__ float p_lds[256][20];
    __shared__ float red[4][16];
    __shared__ float m_lds[16], l_lds[16], alpha_lds[16];

    int blk = blockIdx.x;
    int b   = blk / (NSP/16);
    int i0  = (blk % (NSP/16)) * 16;
    int t    = threadIdx.x;
    int lane = t & 63;
    int wave = t >> 6;
    int c  = t & 63;
    int rg = t >> 6;

    if (t < 128) {
        int r = t >> 3, o = t & 7;
        q_lds[r][o] = Qi[((size_t)(b*C8 + o))*NSP + i0 + r];
    }
    if (t < 16) { m_lds[t] = -1e30f; l_lds[t] = 0.f; }
    float acc0 = 0.f, acc1 = 0.f, acc2 = 0.f, acc3 = 0.f;
    __syncthreads();

    for (int j0 = 0; j0 < NSP; j0 += 256) {
        int j = j0 + t;
        float kv[8];
        #pragma unroll
        for (int o = 0; o < 8; ++o)
            kv[o] = Ki[((size_t)(b*C8 + o))*NSP + j];
        float e[16];
        #pragma unroll
        for (int r = 0; r < 16; ++r) {
            float4 qa = *(const float4*)&q_lds[r][0];
            float4 qb = *(const float4*)&q_lds[r][4];
            e[r] = qa.x*kv[0] + qa.y*kv[1] + qa.z*kv[2] + qa.w*kv[3]
                 + qb.x*kv[4] + qb.y*kv[5] + qb.z*kv[6] + qb.w*kv[7];
        }
        #pragma unroll
        for (int r = 0; r < 16; ++r) {
            float v = e[r];
            for (int off = 32; off > 0; off >>= 1)
                v = fmaxf(v, __shfl_xor(v, off));
            if (lane == 0) red[wave][r] = v;
        }
        __syncthreads();
        if (t < 16) {
            float cm = fmaxf(fmaxf(red[0][t], red[1][t]), fmaxf(red[2][t], red[3][t]));
            float m_old = m_lds[t];
            float m_new = fmaxf(m_old, cm);
            m_lds[t] = m_new;
            alpha_lds[t] = __expf(m_old - m_new);
        }
        __syncthreads();
        #pragma unroll
        for (int r = 0; r < 16; ++r) {
            float p = __expf(e[r] - m_lds[r]);
            e[r] = p;
            float s = p;
            for (int off = 32; off > 0; off >>= 1)
                s += __shfl_xor(s, off);
            if (lane == 0) red[wave][r] = s;
        }
        *(float4*)&p_lds[t][0]  = make_float4(e[0],  e[1],  e[2],  e[3]);
        *(float4*)&p_lds[t][4]  = make_float4(e[4],  e[5],  e[6],  e[7]);
        *(float4*)&p_lds[t][8]  = make_float4(e[8],  e[9],  e[10], e[11]);
        *(float4*)&p_lds[t][12] = make_float4(e[12], e[13], e[14], e[15]);
        __syncthreads();
        if (t < 16)
            l_lds[t] = l_lds[t]*alpha_lds[t]
                     + (red[0][t] + red[1][t] + red[2][t] + red[3][t]);
        float al0 = alpha_lds[rg*4 + 0];
        float al1 = alpha_lds[rg*4 + 1];
        float al2 = alpha_lds[rg*4 + 2];
        float al3 = alpha_lds[rg*4 + 3];
        acc0 *= al0; acc1 *= al1; acc2 *= al2; acc3 *= al3;
        const float* vt = VT + (((size_t)b)*NSP + j0)*CHN + c;
        for (int jj = 0; jj < 256; ++jj) {
            float vv = vt[(size_t)jj*CHN];
            float4 p4 = *(const float4*)&p_lds[jj][rg*4];
            acc0 = fmaf(p4.x, vv, acc0);
            acc1 = fmaf(p4.y, vv, acc1);
            acc2 = fmaf(p4.z, vv, acc2);
            acc3 = fmaf(p4.w, vv, acc3);
        }
        __syncthreads();
    }
    float g = gamma_p[0];
    float li[4] = { 1.f/l_lds[rg*4+0], 1.f/l_lds[rg*4+1],
                    1.f/l_lds[rg*4+2], 1.f/l_lds[rg*4+3] };
    float ac[4] = { acc0, acc1, acc2, acc3 };
    size_t base = ((size_t)(b*CHN + c))*NSP + i0;
    #pragma unroll
    for (int k = 0; k < 4; ++k) {
        int i_k = i0 + rg*4 + k;
        int iy = i_k / WW, ix = i_k - iy*WW;
        int np = (iy + 1)*PW + ix + 1;
        float Fv = FR[((size_t)b*PN + np)*CHN + c];
        out[base + rg*4 + k] = g*(ac[k]*li[k]) + Fv;
    }
}

// ---------------------------------------------------------------------------
// conv 9x9 (64 -> 3), pad 4, + tanh  (reads co-major fp32 from attn output)
__global__ __launch_bounds__(256) void k_conv_out(const float* __restrict__ in,
        const float* __restrict__ w, const float* __restrict__ bias,
        float* __restrict__ out) {
    int idx = blockIdx.x * 256 + threadIdx.x;
    if (idx >= BATCH*CIN*NSP) return;
    int n  = idx % NSP;
    int co = (idx / NSP) % CIN;
    int b  = idx / (NSP*CIN);
    int y = n / WW, xx = n % WW;
    float sum = bias[co];
    int ky0 = max(0, 4 - y),  ky1 = min(9, 100 - y);
    int kx0 = max(0, 4 - xx), kx1 = min(9, 100 - xx);
    for (int ci = 0; ci < CHN; ++ci) {
        const float* xin = in + ((size_t)(b*CHN + ci))*NSP;
        const float* wp  = w + ((size_t)(co*CHN + ci))*81;
        for (int ky = ky0; ky < ky1; ++ky) {
            const float* row = xin + (y + ky - 4)*WW + (xx - 4);
            const float* wr  = wp + ky*9;
            for (int kx = kx0; kx < kx1; ++kx)
                sum = fmaf(row[kx], wr[kx], sum);
        }
    }
    out[idx] = tanhf(sum);
}

// ---------------------------------------------------------------------------
extern "C" void kernel_launch(void* const* d_in, const int* in_sizes, int n_in,
                              void* d_out, int out_size, void* d_ws, size_t ws_size,
                              hipStream_t stream) {
    (void)in_sizes; (void)n_in; (void)out_size; (void)ws_size;
    const float* x     = (const float*)d_in[0];
    const float* w_in  = (const float*)d_in[1];
    const float* b_in  = (const float*)d_in[2];
    const float* a_in  = (const float*)d_in[3];
    const float* rw1   = (const float*)d_in[4];
    const float* rb1   = (const float*)d_in[5];
    const float* ra    = (const float*)d_in[6];
    const float* rw2   = (const float*)d_in[7];
    const float* rb2   = (const float*)d_in[8];
    const float* wq    = (const float*)d_in[9];
    const float* bq    = (const float*)d_in[10];
    const float* wk    = (const float*)d_in[11];
    const float* bk    = (const float*)d_in[12];
    const float* wv    = (const float*)d_in[13];
    const float* bv    = (const float*)d_in[14];
    const float* gamma = (const float*)d_in[15];
    const float* w_out = (const float*)d_in[16];
    const float* b_out = (const float*)d_in[17];

    // workspace layout (bytes)
    const size_t SZ_FR  = (size_t)BATCH*PN*CHN*4;        // 4,917,248
    const size_t SZ_FB  = (size_t)BATCH*FBSTRIDE*2;      // 2,524,160
    const size_t SZ_WT  = (size_t)NBLK*2*9*CHN*CHN*2;    //   737,280
    const size_t SZ_Q   = (size_t)BATCH*C8*NSP*4;        //   589,824
    const size_t SZ_VT  = (size_t)BATCH*NSP*CHN*4;       // 4,718,592
    char* p = (char*)d_ws;
    float* FR      = (float*)p;           p += SZ_FR;
    short* FBh0raw = (short*)p;           p += SZ_FB;
    short* FBl0raw = (short*)p;           p += SZ_FB;
    short* FBh1raw = (short*)p;           p += SZ_FB;
    short* FBl1raw = (short*)p;           p += SZ_FB;
    short* Whi     = (short*)p;           p += SZ_WT;
    short* Wlo     = (short*)p;           p += SZ_WT;
    float* Qb      = (float*)p;           p += SZ_Q;
    float* Kb      = (float*)p;           p += SZ_Q;
    float* VT      = (float*)p;           p += SZ_VT;
    float* Bf      = (float*)p;           p += SZ_VT;
    short* FBh0 = FBh0raw + GUARD*CHN;
    short* FBl0 = FBl0raw + GUARD*CHN;
    short* FBh1 = FBh1raw + GUARD*CHN;
    short* FBl1 = FBl1raw + GUARD*CHN;
    float* outp = (float*)d_out;

    hipMemsetAsync(FR, 0, SZ_FR, stream);
    hipMemsetAsync(FBh0raw, 0, SZ_FB, stream);
    hipMemsetAsync(FBl0raw, 0, SZ_FB, stream);
    hipMemsetAsync(FBh1raw, 0, SZ_FB, stream);
    hipMemsetAsync(FBl1raw, 0, SZ_FB, stream);

    const int feat = BATCH*CHN*NSP;
    dim3 blk(256);

    k_prep_w<<<(NBLK*2*9*CHN*CHN + 255)/256, blk, 0, stream>>>(rw1, rw2, Whi, Wlo);
    k_conv_in<<<(feat + 255)/256, blk, 0, stream>>>(x, w_in, b_in, a_in, FR, FBh0, FBl0);
    for (int i = 0; i < NBLK; ++i) {
        k_conv3_mfma<<<BATCH*147, blk, 0, stream>>>(
            FBh0, FBl0,
            Whi + (size_t)(2*i)*9*CHN*CHN, Wlo + (size_t)(2*i)*9*CHN*CHN,
            rb1 + i*CHN, ra + i, (float*)nullptr, FBh1, FBl1, 0);
        k_conv3_mfma<<<BATCH*147, blk, 0, stream>>>(
            FBh1, FBl1,
            Whi + (size_t)(2*i+1)*9*CHN*CHN, Wlo + (size_t)(2*i+1)*9*CHN*CHN,
            rb2 + i*CHN, ra + i, FR, FBh0, FBl0, 1);
    }
    k_qkv<<<(BATCH*NSP + 255)/256, blk, 0, stream>>>(
        FR, wq, bq, wk, bk, wv, bv, Qb, Kb, VT);
    k_attn<<<BATCH*(NSP/16), blk, 0, stream>>>(Qb, Kb, VT, FR, gamma, Bf);
    k_conv_out<<<(BATCH*CIN*NSP + 255)/256, blk, 0, stream>>>(Bf, w_out, b_out, outp);
}

// Round 4
// 1596.730 us; speedup vs baseline: 2.9775x; 1.6154x over previous
//
#include <hip/hip_runtime.h>
#include <cmath>

#define BATCH 2
#define CIN 3
#define HH 96
#define WW 96
#define NSP (HH*WW)      // 9216
#define CHN 64
#define C8 8
#define NBLK 5

#define PW 98            // padded width/height
#define PN (PW*PW)       // 9604 padded spatial
#define GUARD 128        // guard entries (spatial) each side of FB buffers
#define FBSTRIDE ((PN + 2*GUARD)*CHN)   // shorts per batch in FB buffers

#define PST 72           // p_lds row stride in shorts (144B, 16B-aligned)

typedef __attribute__((ext_vector_type(8))) short bf16x8;
typedef __attribute__((ext_vector_type(4))) float f32x4;

static __device__ __forceinline__ short f2b(float f) {
    union { float f; unsigned u; } v; v.f = f;
    unsigned r = (v.u + 0x7FFFu + ((v.u >> 16) & 1u)) >> 16;
    return (short)r;
}
static __device__ __forceinline__ float b2f(short s) {
    union { unsigned u; float f; } v; v.u = ((unsigned)(unsigned short)s) << 16;
    return v.f;
}
static __device__ __forceinline__ void split2(float v, short& hi, short& lo) {
    hi = f2b(v);
    lo = f2b(v - b2f(hi));
}

// ---------------------------------------------------------------------------
// weight prep: rw[blk][co][ci][3][3] fp32 -> Whi/Wlo[conv][kyx][co][ci] bf16
__global__ __launch_bounds__(256) void k_prep_w(const float* __restrict__ rw1,
        const float* __restrict__ rw2, short* __restrict__ Whi,
        short* __restrict__ Wlo) {
    int idx = blockIdx.x * 256 + threadIdx.x;
    const int TOT = NBLK*2*9*CHN*CHN;
    if (idx >= TOT) return;
    int ci  = idx & 63;
    int co  = (idx >> 6) & 63;
    int kyx = (idx >> 12) % 9;
    int conv = idx / (9*CHN*CHN);
    int blk = conv >> 1, s = conv & 1;
    const float* src = s ? rw2 : rw1;
    float v = src[(((size_t)(blk*CHN + co))*CHN + ci)*9 + kyx];
    short h, l; split2(v, h, l);
    Whi[idx] = h; Wlo[idx] = l;
}

// ---------------------------------------------------------------------------
// conv 9x9 (3 -> 64), pad 4, + PReLU -> FR (fp32 n-major padded) + FBhi/FBlo
__global__ __launch_bounds__(256) void k_conv_in(const float* __restrict__ x,
        const float* __restrict__ w, const float* __restrict__ bias,
        const float* __restrict__ a, float* __restrict__ FR,
        short* __restrict__ FBhi, short* __restrict__ FBlo) {
    int idx = blockIdx.x * 256 + threadIdx.x;
    if (idx >= BATCH*CHN*NSP) return;
    int n  = idx % NSP;
    int co = (idx / NSP) % CHN;
    int b  = idx / (NSP*CHN);
    int y = n / WW, xx = n % WW;
    float sum = bias[co];
    int ky0 = max(0, 4 - y),  ky1 = min(9, 100 - y);
    int kx0 = max(0, 4 - xx), kx1 = min(9, 100 - xx);
    for (int ci = 0; ci < CIN; ++ci) {
        const float* xin = x + ((size_t)(b*CIN + ci))*NSP;
        const float* wp  = w + ((size_t)(co*CIN + ci))*81;
        for (int ky = ky0; ky < ky1; ++ky) {
            const float* row = xin + (y + ky - 4)*WW + (xx - 4);
            const float* wr  = wp + ky*9;
            for (int kx = kx0; kx < kx1; ++kx)
                sum = fmaf(row[kx], wr[kx], sum);
        }
    }
    float sl = a[0];
    float v = sum >= 0.f ? sum : sl*sum;
    int np = (y + 1)*PW + xx + 1;
    FR[((size_t)b*PN + np)*CHN + co] = v;
    short h, l; split2(v, h, l);
    FBhi[(size_t)b*FBSTRIDE + (size_t)np*CHN + co] = h;
    FBlo[(size_t)b*FBSTRIDE + (size_t)np*CHN + co] = l;
}

// ---------------------------------------------------------------------------
// 3x3 conv 64->64, implicit GEMM, split-bf16 3-MFMA (~fp32 precision).
__global__ __launch_bounds__(256) void k_conv3_mfma(
        const short* __restrict__ FBhi_in, const short* __restrict__ FBlo_in,
        const short* __restrict__ Whi, const short* __restrict__ Wlo,
        const float* __restrict__ bias, const float* __restrict__ slope_p,
        float* __restrict__ FR,
        short* __restrict__ FBhi_out, short* __restrict__ FBlo_out, int mode) {
    int t = threadIdx.x;
    int w = t >> 6, lane = t & 63;
    int q = lane >> 4, n16 = lane & 15;
    int blk = blockIdx.x;
    int b = blk / 147, chunk = blk % 147;
    int nb = 98 + chunk*64 + w*16 + n16;

    const short* fbh = FBhi_in + (size_t)b*FBSTRIDE;
    const short* fbl = FBlo_in + (size_t)b*FBSTRIDE;
    f32x4 acc[4] = {{0,0,0,0},{0,0,0,0},{0,0,0,0},{0,0,0,0}};

    int nbase = nb*CHN;
    #pragma unroll
    for (int kyx = 0; kyx < 9; ++kyx) {
        int dy = kyx/3 - 1, dx = kyx%3 - 1;
        int boff = nbase + (dy*PW + dx)*CHN;
        const short* wph = Whi + (size_t)kyx*CHN*CHN;
        const short* wpl = Wlo + (size_t)kyx*CHN*CHN;
        #pragma unroll
        for (int cih = 0; cih < 2; ++cih) {
            int xoff = boff + cih*32 + q*8;
            bf16x8 bhi = *(const bf16x8*)(fbh + xoff);
            bf16x8 blo = *(const bf16x8*)(fbl + xoff);
            #pragma unroll
            for (int ct = 0; ct < 4; ++ct) {
                int aoff = (ct*16 + n16)*CHN + cih*32 + q*8;
                bf16x8 ahi = *(const bf16x8*)(wph + aoff);
                bf16x8 alo = *(const bf16x8*)(wpl + aoff);
                acc[ct] = __builtin_amdgcn_mfma_f32_16x16x32_bf16(ahi, bhi, acc[ct], 0, 0, 0);
                acc[ct] = __builtin_amdgcn_mfma_f32_16x16x32_bf16(ahi, blo, acc[ct], 0, 0, 0);
                acc[ct] = __builtin_amdgcn_mfma_f32_16x16x32_bf16(alo, bhi, acc[ct], 0, 0, 0);
            }
        }
    }

    int yy = nb / PW;
    int xx = nb - yy*PW;
    if (xx < 1 || xx > 96 || yy < 1 || yy > 96) return;
    float sl = slope_p[0];
    short* fboh = FBhi_out + (size_t)b*FBSTRIDE + (size_t)nb*CHN;
    short* fbol = FBlo_out + (size_t)b*FBSTRIDE + (size_t)nb*CHN;
    float* fr  = FR + ((size_t)b*PN + nb)*CHN;
    #pragma unroll
    for (int ct = 0; ct < 4; ++ct) {
        #pragma unroll
        for (int r = 0; r < 4; ++r) {
            int co = ct*16 + q*4 + r;
            float v = acc[ct][r] + bias[co];
            if (mode == 0) {
                v = v >= 0.f ? v : sl*v;
            } else {
                v += fr[co];
                fr[co] = v;
            }
            short h, l; split2(v, h, l);
            fboh[co] = h;
            fbol[co] = l;
        }
    }
}

// ---------------------------------------------------------------------------
// 1x1 projections from FR (n-major fp32):
//   Qb16[b][n][8] bf16, Kb16[b][n][8] bf16, Vb16[b][c][N] bf16
__global__ __launch_bounds__(256) void k_qkv(const float* __restrict__ FR,
        const float* __restrict__ wq, const float* __restrict__ bq,
        const float* __restrict__ wk, const float* __restrict__ bk,
        const float* __restrict__ wv, const float* __restrict__ bv,
        short* __restrict__ Qb, short* __restrict__ Kb, short* __restrict__ Vb) {
    int idx = blockIdx.x * 256 + threadIdx.x;   // b*NSP + n
    if (idx >= BATCH*NSP) return;
    int b = idx / NSP, n = idx % NSP;
    int y = n / WW, xx = n % WW;
    int np = (y + 1)*PW + xx + 1;
    const float* xp = FR + ((size_t)b*PN + np)*CHN;
    float xv[CHN];
    #pragma unroll
    for (int c = 0; c < CHN; c += 4) {
        float4 f4 = *(const float4*)(xp + c);
        xv[c] = f4.x; xv[c+1] = f4.y; xv[c+2] = f4.z; xv[c+3] = f4.w;
    }
    bf16x8 qs, ks;
    #pragma unroll
    for (int o = 0; o < C8; ++o) {
        float qv = bq[o], kv = bk[o];
        #pragma unroll
        for (int c = 0; c < CHN; ++c) {
            qv = fmaf(wq[o*CHN + c], xv[c], qv);
            kv = fmaf(wk[o*CHN + c], xv[c], kv);
        }
        qs[o] = f2b(qv);
        ks[o] = f2b(kv);
    }
    *(bf16x8*)(Qb + (size_t)idx*8) = qs;
    *(bf16x8*)(Kb + (size_t)idx*8) = ks;
    for (int o = 0; o < CHN; ++o) {
        float v = bv[o];
        #pragma unroll
        for (int c = 0; c < CHN; ++c)
            v = fmaf(wv[o*CHN + c], xv[c], v);
        Vb[((size_t)(b*CHN + o))*NSP + n] = f2b(v);
    }
}

// ---------------------------------------------------------------------------
// MFMA flash attention. Block = 128 threads = 2 waves; both waves own the same
// 16 query rows (i0..i0+15); wave w processes j in [w*4608, (w+1)*4608).
// Energy: mfma 16x16x32 bf16, K-dim = 8 channels padded to 32 (quads 1-3 zero).
// P transposed C-layout -> A-layout through per-wave LDS tile.
// PV: 8 MFMA per 64-j chunk, V read as [c][N] bf16 contiguous B-frags.
// Final: cross-wave merge of (m,l,O), out = gamma*O/l + FR residual.
__global__ __launch_bounds__(128) void k_attn_mfma(
        const short* __restrict__ Qb, const short* __restrict__ Kb,
        const short* __restrict__ Vb, const float* __restrict__ FR,
        const float* __restrict__ gamma_p, float* __restrict__ out) {
    __shared__ short p_lds[2][16][PST];
    __shared__ float Osh[2][16][65];
    __shared__ float msh[2][16], lsh[2][16];

    int blk = blockIdx.x;
    int b  = blk / (NSP/16);
    int i0 = (blk % (NSP/16)) * 16;
    int t = threadIdx.x;
    int w = t >> 6;
    int lane = t & 63;
    int quad = lane >> 4, n16 = lane & 15;

    const short* Qp = Qb + ((size_t)b*NSP)*8;
    const short* Kp = Kb + ((size_t)b*NSP)*8;
    const short* Vp = Vb + ((size_t)b*CHN)*NSP;

    bf16x8 qf = {0,0,0,0,0,0,0,0};
    if (quad == 0) qf = *(const bf16x8*)(Qp + (size_t)(i0 + n16)*8);

    f32x4 accO[4] = {{0,0,0,0},{0,0,0,0},{0,0,0,0},{0,0,0,0}};
    float m[4] = {-1e30f,-1e30f,-1e30f,-1e30f};
    float l[4] = {0.f,0.f,0.f,0.f};

    short* pl = &p_lds[w][0][0];

    for (int jc = 0; jc < 72; ++jc) {
        int j0 = w*4608 + jc*64;
        // ---- energy: 4 tiles of 16 j ----
        f32x4 e[4];
        #pragma unroll
        for (int tt = 0; tt < 4; ++tt) {
            bf16x8 kf = {0,0,0,0,0,0,0,0};
            if (quad == 0)
                kf = *(const bf16x8*)(Kp + (size_t)(j0 + tt*16 + n16)*8);
            f32x4 z = {0.f,0.f,0.f,0.f};
            e[tt] = __builtin_amdgcn_mfma_f32_16x16x32_bf16(qf, kf, z, 0, 0, 0);
        }
        // ---- online softmax (rows r -> global row quad*4+r) ----
        float alpha[4];
        #pragma unroll
        for (int r = 0; r < 4; ++r) {
            float v = fmaxf(fmaxf(e[0][r], e[1][r]), fmaxf(e[2][r], e[3][r]));
            v = fmaxf(v, __shfl_xor(v, 1));
            v = fmaxf(v, __shfl_xor(v, 2));
            v = fmaxf(v, __shfl_xor(v, 4));
            v = fmaxf(v, __shfl_xor(v, 8));
            float mn = fmaxf(m[r], v);
            alpha[r] = __expf(m[r] - mn);
            m[r] = mn;
        }
        #pragma unroll
        for (int r = 0; r < 4; ++r) {
            float s = 0.f;
            #pragma unroll
            for (int tt = 0; tt < 4; ++tt) {
                float p = __expf(e[tt][r] - m[r]);
                e[tt][r] = p;
                s += p;
                pl[(quad*4 + r)*PST + tt*16 + n16] = f2b(p);
            }
            s += __shfl_xor(s, 1);
            s += __shfl_xor(s, 2);
            s += __shfl_xor(s, 4);
            s += __shfl_xor(s, 8);
            l[r] = l[r]*alpha[r] + s;
        }
        // rescale O accumulators
        #pragma unroll
        for (int ct = 0; ct < 4; ++ct)
            #pragma unroll
            for (int r = 0; r < 4; ++r)
                accO[ct][r] *= alpha[r];
        __syncthreads();
        // ---- PV: P (A-layout from LDS) x V ([c][N] B-frags) ----
        #pragma unroll
        for (int ks = 0; ks < 2; ++ks) {
            bf16x8 pf = *(const bf16x8*)(pl + n16*PST + ks*32 + quad*8);
            #pragma unroll
            for (int ct = 0; ct < 4; ++ct) {
                bf16x8 vf = *(const bf16x8*)(Vp + (size_t)(ct*16 + n16)*NSP
                                             + j0 + ks*32 + quad*8);
                accO[ct] = __builtin_amdgcn_mfma_f32_16x16x32_bf16(pf, vf, accO[ct], 0, 0, 0);
            }
        }
        __syncthreads();
    }

    // ---- write per-wave partials ----
    #pragma unroll
    for (int ct = 0; ct < 4; ++ct)
        #pragma unroll
        for (int r = 0; r < 4; ++r)
            Osh[w][quad*4 + r][ct*16 + n16] = accO[ct][r];
    if (n16 == 0) {
        #pragma unroll
        for (int r = 0; r < 4; ++r) {
            msh[w][quad*4 + r] = m[r];
            lsh[w][quad*4 + r] = l[r];
        }
    }
    __syncthreads();

    // ---- merge two waves, add residual, store ----
    float g = gamma_p[0];
    int c = t & 63;
    int half = t >> 6;
    #pragma unroll
    for (int ii = 0; ii < 8; ++ii) {
        int i = ii*2 + half;
        float ma = msh[0][i], mb = msh[1][i];
        float mm = fmaxf(ma, mb);
        float ea = __expf(ma - mm), eb = __expf(mb - mm);
        float ll = ea*lsh[0][i] + eb*lsh[1][i];
        float Ov = ea*Osh[0][i][c] + eb*Osh[1][i][c];
        int gi = i0 + i;
        int iy = gi / WW, ix = gi - iy*WW;
        int np = (iy + 1)*PW + ix + 1;
        float Fv = FR[((size_t)b*PN + np)*CHN + c];
        out[((size_t)(b*CHN + c))*NSP + gi] = g*(Ov/ll) + Fv;
    }
}

// ---------------------------------------------------------------------------
// conv 9x9 (64 -> 3), pad 4, + tanh  (reads co-major fp32 from attn output)
__global__ __launch_bounds__(256) void k_conv_out(const float* __restrict__ in,
        const float* __restrict__ w, const float* __restrict__ bias,
        float* __restrict__ out) {
    int idx = blockIdx.x * 256 + threadIdx.x;
    if (idx >= BATCH*CIN*NSP) return;
    int n  = idx % NSP;
    int co = (idx / NSP) % CIN;
    int b  = idx / (NSP*CIN);
    int y = n / WW, xx = n % WW;
    float sum = bias[co];
    int ky0 = max(0, 4 - y),  ky1 = min(9, 100 - y);
    int kx0 = max(0, 4 - xx), kx1 = min(9, 100 - xx);
    for (int ci = 0; ci < CHN; ++ci) {
        const float* xin = in + ((size_t)(b*CHN + ci))*NSP;
        const float* wp  = w + ((size_t)(co*CHN + ci))*81;
        for (int ky = ky0; ky < ky1; ++ky) {
            const float* row = xin + (y + ky - 4)*WW + (xx - 4);
            const float* wr  = wp + ky*9;
            for (int kx = kx0; kx < kx1; ++kx)
                sum = fmaf(row[kx], wr[kx], sum);
        }
    }
    out[idx] = tanhf(sum);
}

// ---------------------------------------------------------------------------
extern "C" void kernel_launch(void* const* d_in, const int* in_sizes, int n_in,
                              void* d_out, int out_size, void* d_ws, size_t ws_size,
                              hipStream_t stream) {
    (void)in_sizes; (void)n_in; (void)out_size; (void)ws_size;
    const float* x     = (const float*)d_in[0];
    const float* w_in  = (const float*)d_in[1];
    const float* b_in  = (const float*)d_in[2];
    const float* a_in  = (const float*)d_in[3];
    const float* rw1   = (const float*)d_in[4];
    const float* rb1   = (const float*)d_in[5];
    const float* ra    = (const float*)d_in[6];
    const float* rw2   = (const float*)d_in[7];
    const float* rb2   = (const float*)d_in[8];
    const float* wq    = (const float*)d_in[9];
    const float* bq    = (const float*)d_in[10];
    const float* wk    = (const float*)d_in[11];
    const float* bk    = (const float*)d_in[12];
    const float* wv    = (const float*)d_in[13];
    const float* bv    = (const float*)d_in[14];
    const float* gamma = (const float*)d_in[15];
    const float* w_out = (const float*)d_in[16];
    const float* b_out = (const float*)d_in[17];

    // workspace layout (bytes), all chunks 16B-aligned
    const size_t SZ_FR  = (size_t)BATCH*PN*CHN*4;        // 4,917,248
    const size_t SZ_FB  = (size_t)BATCH*FBSTRIDE*2;      // 2,524,160
    const size_t SZ_WT  = (size_t)NBLK*2*9*CHN*CHN*2;    //   737,280
    const size_t SZ_QK  = (size_t)BATCH*NSP*C8*2;        //   294,912
    const size_t SZ_VB  = (size_t)BATCH*CHN*NSP*2;       // 2,359,296
    const size_t SZ_BF  = (size_t)BATCH*CHN*NSP*4;       // 4,718,592
    char* p = (char*)d_ws;
    float* FR      = (float*)p;           p += SZ_FR;
    short* FBh0raw = (short*)p;           p += SZ_FB;
    short* FBl0raw = (short*)p;           p += SZ_FB;
    short* FBh1raw = (short*)p;           p += SZ_FB;
    short* FBl1raw = (short*)p;           p += SZ_FB;
    short* Whi     = (short*)p;           p += SZ_WT;
    short* Wlo     = (short*)p;           p += SZ_WT;
    short* Qb16    = (short*)p;           p += SZ_QK;
    short* Kb16    = (short*)p;           p += SZ_QK;
    short* Vb16    = (short*)p;           p += SZ_VB;
    float* Bf      = (float*)p;           p += SZ_BF;
    short* FBh0 = FBh0raw + GUARD*CHN;
    short* FBl0 = FBl0raw + GUARD*CHN;
    short* FBh1 = FBh1raw + GUARD*CHN;
    short* FBl1 = FBl1raw + GUARD*CHN;
    float* outp = (float*)d_out;

    hipMemsetAsync(FR, 0, SZ_FR, stream);
    hipMemsetAsync(FBh0raw, 0, SZ_FB, stream);
    hipMemsetAsync(FBl0raw, 0, SZ_FB, stream);
    hipMemsetAsync(FBh1raw, 0, SZ_FB, stream);
    hipMemsetAsync(FBl1raw, 0, SZ_FB, stream);

    const int feat = BATCH*CHN*NSP;
    dim3 blk(256);

    k_prep_w<<<(NBLK*2*9*CHN*CHN + 255)/256, blk, 0, stream>>>(rw1, rw2, Whi, Wlo);
    k_conv_in<<<(feat + 255)/256, blk, 0, stream>>>(x, w_in, b_in, a_in, FR, FBh0, FBl0);
    for (int i = 0; i < NBLK; ++i) {
        k_conv3_mfma<<<BATCH*147, blk, 0, stream>>>(
            FBh0, FBl0,
            Whi + (size_t)(2*i)*9*CHN*CHN, Wlo + (size_t)(2*i)*9*CHN*CHN,
            rb1 + i*CHN, ra + i, (float*)nullptr, FBh1, FBl1, 0);
        k_conv3_mfma<<<BATCH*147, blk, 0, stream>>>(
            FBh1, FBl1,
            Whi + (size_t)(2*i+1)*9*CHN*CHN, Wlo + (size_t)(2*i+1)*9*CHN*CHN,
            rb2 + i*CHN, ra + i, FR, FBh0, FBl0, 1);
    }
    k_qkv<<<(BATCH*NSP + 255)/256, blk, 0, stream>>>(
        FR, wq, bq, wk, bk, wv, bv, Qb16, Kb16, Vb16);
    k_attn_mfma<<<BATCH*(NSP/16), dim3(128), 0, stream>>>(
        Qb16, Kb16, Vb16, FR, gamma, Bf);
    k_conv_out<<<(BATCH*CIN*NSP + 255)/256, blk, 0, stream>>>(Bf, w_out, b_out, outp);
}

// Round 5
// 1002.491 us; speedup vs baseline: 4.7425x; 1.5928x over previous
//
#include <hip/hip_runtime.h>
#include <cmath>

#define BATCH 2
#define CIN 3
#define HH 96
#define WW 96
#define NSP (HH*WW)      // 9216
#define CHN 64
#define C8 8
#define NBLK 5

#define PW 98            // padded width/height (3x3 convs)
#define PN (PW*PW)       // 9604 padded spatial
#define GUARD 128        // guard entries (spatial) each side of FB buffers
#define FBSTRIDE ((PN + 2*GUARD)*CHN)   // shorts per batch in FB buffers

#define PW2 104          // padded width for 9x9 conv_out input
#define PN2 (PW2*PW2)    // 10816

#define PST 72           // p_lds row stride in shorts (144B, 16B-aligned)

typedef __attribute__((ext_vector_type(8))) short bf16x8;
typedef __attribute__((ext_vector_type(4))) float f32x4;

static __device__ __forceinline__ short f2b(float f) {
    union { float f; unsigned u; } v; v.f = f;
    unsigned r = (v.u + 0x7FFFu + ((v.u >> 16) & 1u)) >> 16;
    return (short)r;
}
static __device__ __forceinline__ float b2f(short s) {
    union { unsigned u; float f; } v; v.u = ((unsigned)(unsigned short)s) << 16;
    return v.f;
}
static __device__ __forceinline__ void split2(float v, short& hi, short& lo) {
    hi = f2b(v);
    lo = f2b(v - b2f(hi));
}

// ---------------------------------------------------------------------------
// weight prep: rw[blk][co][ci][3][3] fp32 -> Whi/Wlo[conv][kyx][co][ci] bf16
__global__ __launch_bounds__(256) void k_prep_w(const float* __restrict__ rw1,
        const float* __restrict__ rw2, short* __restrict__ Whi,
        short* __restrict__ Wlo) {
    int idx = blockIdx.x * 256 + threadIdx.x;
    const int TOT = NBLK*2*9*CHN*CHN;
    if (idx >= TOT) return;
    int ci  = idx & 63;
    int co  = (idx >> 6) & 63;
    int kyx = (idx >> 12) % 9;
    int conv = idx / (9*CHN*CHN);
    int blk = conv >> 1, s = conv & 1;
    const float* src = s ? rw2 : rw1;
    float v = src[(((size_t)(blk*CHN + co))*CHN + ci)*9 + kyx];
    short h, l; split2(v, h, l);
    Whi[idx] = h; Wlo[idx] = l;
}

// qkv weight prep: -> Wq[co=0..79][ci] bf16 hi/lo (0-7 wq, 8-15 wk, 16-79 wv)
__global__ __launch_bounds__(256) void k_prep_wqkv(const float* __restrict__ wq,
        const float* __restrict__ wk, const float* __restrict__ wv,
        short* __restrict__ Wh, short* __restrict__ Wl) {
    int idx = blockIdx.x * 256 + threadIdx.x;
    if (idx >= 80*CHN) return;
    int ci = idx & 63, co = idx >> 6;
    float v;
    if (co < 8)       v = wq[co*CHN + ci];
    else if (co < 16) v = wk[(co-8)*CHN + ci];
    else              v = wv[(co-16)*CHN + ci];
    short h, l; split2(v, h, l);
    Wh[idx] = h; Wl[idx] = l;
}

// conv_out weight prep: w_out[co][ci][81] fp32 -> Wo[kyx][co][ci] fp32
__global__ __launch_bounds__(256) void k_prep_wout(const float* __restrict__ w_out,
        float* __restrict__ Wo) {
    int idx = blockIdx.x * 256 + threadIdx.x;
    if (idx >= 81*CIN*CHN) return;
    int ci = idx & 63;
    int co = (idx >> 6) % 3;
    int kyx = idx / 192;
    Wo[idx] = w_out[((size_t)(co*CHN + ci))*81 + kyx];
}

// ---------------------------------------------------------------------------
// conv 9x9 (3 -> 64), pad 4, + PReLU -> FR (fp32 n-major padded) + FBhi/FBlo
__global__ __launch_bounds__(256) void k_conv_in(const float* __restrict__ x,
        const float* __restrict__ w, const float* __restrict__ bias,
        const float* __restrict__ a, float* __restrict__ FR,
        short* __restrict__ FBhi, short* __restrict__ FBlo) {
    int idx = blockIdx.x * 256 + threadIdx.x;
    if (idx >= BATCH*CHN*NSP) return;
    int n  = idx % NSP;
    int co = (idx / NSP) % CHN;
    int b  = idx / (NSP*CHN);
    int y = n / WW, xx = n % WW;
    float sum = bias[co];
    int ky0 = max(0, 4 - y),  ky1 = min(9, 100 - y);
    int kx0 = max(0, 4 - xx), kx1 = min(9, 100 - xx);
    for (int ci = 0; ci < CIN; ++ci) {
        const float* xin = x + ((size_t)(b*CIN + ci))*NSP;
        const float* wp  = w + ((size_t)(co*CIN + ci))*81;
        for (int ky = ky0; ky < ky1; ++ky) {
            const float* row = xin + (y + ky - 4)*WW + (xx - 4);
            const float* wr  = wp + ky*9;
            for (int kx = kx0; kx < kx1; ++kx)
                sum = fmaf(row[kx], wr[kx], sum);
        }
    }
    float sl = a[0];
    float v = sum >= 0.f ? sum : sl*sum;
    int np = (y + 1)*PW + xx + 1;
    FR[((size_t)b*PN + np)*CHN + co] = v;
    short h, l; split2(v, h, l);
    FBhi[(size_t)b*FBSTRIDE + (size_t)np*CHN + co] = h;
    FBlo[(size_t)b*FBSTRIDE + (size_t)np*CHN + co] = l;
}

// ---------------------------------------------------------------------------
// 3x3 conv 64->64, implicit GEMM, split-bf16 3-MFMA (~fp32 precision).
__global__ __launch_bounds__(256) void k_conv3_mfma(
        const short* __restrict__ FBhi_in, const short* __restrict__ FBlo_in,
        const short* __restrict__ Whi, const short* __restrict__ Wlo,
        const float* __restrict__ bias, const float* __restrict__ slope_p,
        float* __restrict__ FR,
        short* __restrict__ FBhi_out, short* __restrict__ FBlo_out, int mode) {
    int t = threadIdx.x;
    int w = t >> 6, lane = t & 63;
    int q = lane >> 4, n16 = lane & 15;
    int blk = blockIdx.x;
    int b = blk / 147, chunk = blk % 147;
    int nb = 98 + chunk*64 + w*16 + n16;

    const short* fbh = FBhi_in + (size_t)b*FBSTRIDE;
    const short* fbl = FBlo_in + (size_t)b*FBSTRIDE;
    f32x4 acc[4] = {{0,0,0,0},{0,0,0,0},{0,0,0,0},{0,0,0,0}};

    int nbase = nb*CHN;
    #pragma unroll
    for (int kyx = 0; kyx < 9; ++kyx) {
        int dy = kyx/3 - 1, dx = kyx%3 - 1;
        int boff = nbase + (dy*PW + dx)*CHN;
        const short* wph = Whi + (size_t)kyx*CHN*CHN;
        const short* wpl = Wlo + (size_t)kyx*CHN*CHN;
        #pragma unroll
        for (int cih = 0; cih < 2; ++cih) {
            int xoff = boff + cih*32 + q*8;
            bf16x8 bhi = *(const bf16x8*)(fbh + xoff);
            bf16x8 blo = *(const bf16x8*)(fbl + xoff);
            #pragma unroll
            for (int ct = 0; ct < 4; ++ct) {
                int aoff = (ct*16 + n16)*CHN + cih*32 + q*8;
                bf16x8 ahi = *(const bf16x8*)(wph + aoff);
                bf16x8 alo = *(const bf16x8*)(wpl + aoff);
                acc[ct] = __builtin_amdgcn_mfma_f32_16x16x32_bf16(ahi, bhi, acc[ct], 0, 0, 0);
                acc[ct] = __builtin_amdgcn_mfma_f32_16x16x32_bf16(ahi, blo, acc[ct], 0, 0, 0);
                acc[ct] = __builtin_amdgcn_mfma_f32_16x16x32_bf16(alo, bhi, acc[ct], 0, 0, 0);
            }
        }
    }

    int yy = nb / PW;
    int xx = nb - yy*PW;
    if (xx < 1 || xx > 96 || yy < 1 || yy > 96) return;
    float sl = slope_p[0];
    short* fboh = FBhi_out + (size_t)b*FBSTRIDE + (size_t)nb*CHN;
    short* fbol = FBlo_out + (size_t)b*FBSTRIDE + (size_t)nb*CHN;
    float* fr  = FR + ((size_t)b*PN + nb)*CHN;
    #pragma unroll
    for (int ct = 0; ct < 4; ++ct) {
        #pragma unroll
        for (int r = 0; r < 4; ++r) {
            int co = ct*16 + q*4 + r;
            float v = acc[ct][r] + bias[co];
            if (mode == 0) {
                v = v >= 0.f ? v : sl*v;
            } else {
                v += fr[co];
                fr[co] = v;
            }
            short h, l; split2(v, h, l);
            fboh[co] = h;
            fbol[co] = l;
        }
    }
}

// ---------------------------------------------------------------------------
// qkv projection as 1x1-conv implicit GEMM (80 outputs = 8 q + 8 k + 64 v).
// Same structure as k_conv3_mfma, 5 co-tiles, 1 kyx.
__global__ __launch_bounds__(256) void k_qkv_mfma(
        const short* __restrict__ FBhi_in, const short* __restrict__ FBlo_in,
        const short* __restrict__ Wh, const short* __restrict__ Wl,
        const float* __restrict__ bq, const float* __restrict__ bk,
        const float* __restrict__ bv,
        short* __restrict__ Qb, short* __restrict__ Kb, short* __restrict__ Vb) {
    int t = threadIdx.x;
    int w = t >> 6, lane = t & 63;
    int q = lane >> 4, n16 = lane & 15;
    int blk = blockIdx.x;
    int b = blk / 147, chunk = blk % 147;
    int nb = 98 + chunk*64 + w*16 + n16;

    const short* fbh = FBhi_in + (size_t)b*FBSTRIDE;
    const short* fbl = FBlo_in + (size_t)b*FBSTRIDE;
    f32x4 acc[5] = {{0,0,0,0},{0,0,0,0},{0,0,0,0},{0,0,0,0},{0,0,0,0}};

    int nbase = nb*CHN;
    #pragma unroll
    for (int cih = 0; cih < 2; ++cih) {
        int xoff = nbase + cih*32 + q*8;
        bf16x8 bhi = *(const bf16x8*)(fbh + xoff);
        bf16x8 blo = *(const bf16x8*)(fbl + xoff);
        #pragma unroll
        for (int ct = 0; ct < 5; ++ct) {
            int aoff = (ct*16 + n16)*CHN + cih*32 + q*8;
            bf16x8 ahi = *(const bf16x8*)(Wh + aoff);
            bf16x8 alo = *(const bf16x8*)(Wl + aoff);
            acc[ct] = __builtin_amdgcn_mfma_f32_16x16x32_bf16(ahi, bhi, acc[ct], 0, 0, 0);
            acc[ct] = __builtin_amdgcn_mfma_f32_16x16x32_bf16(ahi, blo, acc[ct], 0, 0, 0);
            acc[ct] = __builtin_amdgcn_mfma_f32_16x16x32_bf16(alo, bhi, acc[ct], 0, 0, 0);
        }
    }

    int yy = nb / PW;
    int xx = nb - yy*PW;
    if (xx < 1 || xx > 96 || yy < 1 || yy > 96) return;
    int n = (yy - 1)*WW + (xx - 1);
    #pragma unroll
    for (int ct = 0; ct < 5; ++ct) {
        #pragma unroll
        for (int r = 0; r < 4; ++r) {
            int co = ct*16 + q*4 + r;
            float v = acc[ct][r];
            if (co < 8)
                Qb[((size_t)b*NSP + n)*8 + co] = f2b(v + bq[co]);
            else if (co < 16)
                Kb[((size_t)b*NSP + n)*8 + (co-8)] = f2b(v + bk[co-8]);
            else
                Vb[((size_t)(b*CHN + co-16))*NSP + n] = f2b(v + bv[co-16]);
        }
    }
}

// ---------------------------------------------------------------------------
// MFMA flash attention. Output written n-major into AT[b][np2][64] (padded
// 104x104 for the 9x9 conv_out), residual added from FR.
__global__ __launch_bounds__(128) void k_attn_mfma(
        const short* __restrict__ Qb, const short* __restrict__ Kb,
        const short* __restrict__ Vb, const float* __restrict__ FR,
        const float* __restrict__ gamma_p, float* __restrict__ AT) {
    __shared__ short p_lds[2][16][PST];
    __shared__ float Osh[2][16][65];
    __shared__ float msh[2][16], lsh[2][16];

    int blk = blockIdx.x;
    int b  = blk / (NSP/16);
    int i0 = (blk % (NSP/16)) * 16;
    int t = threadIdx.x;
    int w = t >> 6;
    int lane = t & 63;
    int quad = lane >> 4, n16 = lane & 15;

    const short* Qp = Qb + ((size_t)b*NSP)*8;
    const short* Kp = Kb + ((size_t)b*NSP)*8;
    const short* Vp = Vb + ((size_t)b*CHN)*NSP;

    bf16x8 qf = {0,0,0,0,0,0,0,0};
    if (quad == 0) qf = *(const bf16x8*)(Qp + (size_t)(i0 + n16)*8);

    f32x4 accO[4] = {{0,0,0,0},{0,0,0,0},{0,0,0,0},{0,0,0,0}};
    float m[4] = {-1e30f,-1e30f,-1e30f,-1e30f};
    float l[4] = {0.f,0.f,0.f,0.f};

    short* pl = &p_lds[w][0][0];

    for (int jc = 0; jc < 72; ++jc) {
        int j0 = w*4608 + jc*64;
        f32x4 e[4];
        #pragma unroll
        for (int tt = 0; tt < 4; ++tt) {
            bf16x8 kf = {0,0,0,0,0,0,0,0};
            if (quad == 0)
                kf = *(const bf16x8*)(Kp + (size_t)(j0 + tt*16 + n16)*8);
            f32x4 z = {0.f,0.f,0.f,0.f};
            e[tt] = __builtin_amdgcn_mfma_f32_16x16x32_bf16(qf, kf, z, 0, 0, 0);
        }
        float alpha[4];
        #pragma unroll
        for (int r = 0; r < 4; ++r) {
            float v = fmaxf(fmaxf(e[0][r], e[1][r]), fmaxf(e[2][r], e[3][r]));
            v = fmaxf(v, __shfl_xor(v, 1));
            v = fmaxf(v, __shfl_xor(v, 2));
            v = fmaxf(v, __shfl_xor(v, 4));
            v = fmaxf(v, __shfl_xor(v, 8));
            float mn = fmaxf(m[r], v);
            alpha[r] = __expf(m[r] - mn);
            m[r] = mn;
        }
        #pragma unroll
        for (int r = 0; r < 4; ++r) {
            float s = 0.f;
            #pragma unroll
            for (int tt = 0; tt < 4; ++tt) {
                float p = __expf(e[tt][r] - m[r]);
                e[tt][r] = p;
                s += p;
                pl[(quad*4 + r)*PST + tt*16 + n16] = f2b(p);
            }
            s += __shfl_xor(s, 1);
            s += __shfl_xor(s, 2);
            s += __shfl_xor(s, 4);
            s += __shfl_xor(s, 8);
            l[r] = l[r]*alpha[r] + s;
        }
        #pragma unroll
        for (int ct = 0; ct < 4; ++ct)
            #pragma unroll
            for (int r = 0; r < 4; ++r)
                accO[ct][r] *= alpha[r];
        __syncthreads();
        #pragma unroll
        for (int ks = 0; ks < 2; ++ks) {
            bf16x8 pf = *(const bf16x8*)(pl + n16*PST + ks*32 + quad*8);
            #pragma unroll
            for (int ct = 0; ct < 4; ++ct) {
                bf16x8 vf = *(const bf16x8*)(Vp + (size_t)(ct*16 + n16)*NSP
                                             + j0 + ks*32 + quad*8);
                accO[ct] = __builtin_amdgcn_mfma_f32_16x16x32_bf16(pf, vf, accO[ct], 0, 0, 0);
            }
        }
        __syncthreads();
    }

    #pragma unroll
    for (int ct = 0; ct < 4; ++ct)
        #pragma unroll
        for (int r = 0; r < 4; ++r)
            Osh[w][quad*4 + r][ct*16 + n16] = accO[ct][r];
    if (n16 == 0) {
        #pragma unroll
        for (int r = 0; r < 4; ++r) {
            msh[w][quad*4 + r] = m[r];
            lsh[w][quad*4 + r] = l[r];
        }
    }
    __syncthreads();

    float g = gamma_p[0];
    int c = t & 63;
    int half = t >> 6;
    #pragma unroll
    for (int ii = 0; ii < 8; ++ii) {
        int i = ii*2 + half;
        float ma = msh[0][i], mb = msh[1][i];
        float mm = fmaxf(ma, mb);
        float ea = __expf(ma - mm), eb = __expf(mb - mm);
        float ll = ea*lsh[0][i] + eb*lsh[1][i];
        float Ov = ea*Osh[0][i][c] + eb*Osh[1][i][c];
        int gi = i0 + i;
        int iy = gi / WW, ix = gi - iy*WW;
        int np = (iy + 1)*PW + ix + 1;
        float Fv = FR[((size_t)b*PN + np)*CHN + c];
        int np2 = (iy + 4)*PW2 + ix + 4;
        AT[((size_t)b*PN2 + np2)*CHN + c] = g*(Ov/ll) + Fv;
    }
}

// ---------------------------------------------------------------------------
// conv 9x9 (64 -> 3) + tanh. Wave per 4 pixels, lane = ci, input n-major
// zero-padded AT[b][104*104][64]; transposed weights Wo[kyx][co][ci].
__global__ __launch_bounds__(256) void k_conv_out(const float* __restrict__ AT,
        const float* __restrict__ Wo, const float* __restrict__ bias,
        float* __restrict__ out) {
    int t = threadIdx.x;
    int w = t >> 6, lane = t & 63;
    int base = blockIdx.x*16 + w*4;       // 4 consecutive pixels, same row
    int b = base / NSP;
    int n0 = base % NSP;
    int y0 = n0 / WW, x0 = n0 % WW;       // x0 % 4 == 0, so x0+3 <= 95

    float s[4][3] = {{0,0,0},{0,0,0},{0,0,0},{0,0,0}};
    for (int ky = 0; ky < 9; ++ky) {
        const float* arow = AT + ((size_t)b*PN2 + (size_t)(y0 + ky)*PW2 + x0)*CHN + lane;
        const float* wrow = Wo + (size_t)ky*9*192;
        float xv[12];
        #pragma unroll
        for (int u = 0; u < 12; ++u)
            xv[u] = arow[(size_t)u*CHN];
        #pragma unroll
        for (int kx = 0; kx < 9; ++kx) {
            float w0 = wrow[kx*192 +   0 + lane];
            float w1 = wrow[kx*192 +  64 + lane];
            float w2 = wrow[kx*192 + 128 + lane];
            #pragma unroll
            for (int p = 0; p < 4; ++p) {
                float x = xv[kx + p];
                s[p][0] = fmaf(x, w0, s[p][0]);
                s[p][1] = fmaf(x, w1, s[p][1]);
                s[p][2] = fmaf(x, w2, s[p][2]);
            }
        }
    }
    #pragma unroll
    for (int p = 0; p < 4; ++p)
        #pragma unroll
        for (int c = 0; c < 3; ++c) {
            float v = s[p][c];
            v += __shfl_xor(v, 1);
            v += __shfl_xor(v, 2);
            v += __shfl_xor(v, 4);
            v += __shfl_xor(v, 8);
            v += __shfl_xor(v, 16);
            v += __shfl_xor(v, 32);
            s[p][c] = v;
        }
    #pragma unroll
    for (int p = 0; p < 4; ++p)
        #pragma unroll
        for (int c = 0; c < 3; ++c)
            if (lane == p*3 + c)
                out[((size_t)(b*3 + c))*NSP + n0 + p] = tanhf(s[p][c] + bias[c]);
}

// ---------------------------------------------------------------------------
extern "C" void kernel_launch(void* const* d_in, const int* in_sizes, int n_in,
                              void* d_out, int out_size, void* d_ws, size_t ws_size,
                              hipStream_t stream) {
    (void)in_sizes; (void)n_in; (void)out_size; (void)ws_size;
    const float* x     = (const float*)d_in[0];
    const float* w_in  = (const float*)d_in[1];
    const float* b_in  = (const float*)d_in[2];
    const float* a_in  = (const float*)d_in[3];
    const float* rw1   = (const float*)d_in[4];
    const float* rb1   = (const float*)d_in[5];
    const float* ra    = (const float*)d_in[6];
    const float* rw2   = (const float*)d_in[7];
    const float* rb2   = (const float*)d_in[8];
    const float* wq    = (const float*)d_in[9];
    const float* bq    = (const float*)d_in[10];
    const float* wk    = (const float*)d_in[11];
    const float* bk    = (const float*)d_in[12];
    const float* wv    = (const float*)d_in[13];
    const float* bv    = (const float*)d_in[14];
    const float* gamma = (const float*)d_in[15];
    const float* w_out = (const float*)d_in[16];
    const float* b_out = (const float*)d_in[17];

    // workspace layout (bytes), all chunks 16B-aligned
    const size_t SZ_FR  = (size_t)BATCH*PN*CHN*4;        // 4,917,248
    const size_t SZ_FB  = (size_t)BATCH*FBSTRIDE*2;      // 2,524,160
    const size_t SZ_WT  = (size_t)NBLK*2*9*CHN*CHN*2;    //   737,280
    const size_t SZ_QK  = (size_t)BATCH*NSP*C8*2;        //   294,912
    const size_t SZ_VB  = (size_t)BATCH*CHN*NSP*2;       // 2,359,296
    const size_t SZ_AT  = (size_t)BATCH*PN2*CHN*4;       // 5,537,792
    const size_t SZ_WO  = (size_t)81*CIN*CHN*4;          //    62,208
    const size_t SZ_WQ  = (size_t)80*CHN*2;              //    10,240
    char* p = (char*)d_ws;
    float* FR      = (float*)p;           p += SZ_FR;
    short* FBh0raw = (short*)p;           p += SZ_FB;
    short* FBl0raw = (short*)p;           p += SZ_FB;
    short* FBh1raw = (short*)p;           p += SZ_FB;
    short* FBl1raw = (short*)p;           p += SZ_FB;
    short* Whi     = (short*)p;           p += SZ_WT;
    short* Wlo     = (short*)p;           p += SZ_WT;
    short* Qb16    = (short*)p;           p += SZ_QK;
    short* Kb16    = (short*)p;           p += SZ_QK;
    short* Vb16    = (short*)p;           p += SZ_VB;
    float* AT      = (float*)p;           p += SZ_AT;
    float* Wo      = (float*)p;           p += SZ_WO;
    short* Wqh     = (short*)p;           p += SZ_WQ;
    short* Wql     = (short*)p;           p += SZ_WQ;
    short* FBh0 = FBh0raw + GUARD*CHN;
    short* FBl0 = FBl0raw + GUARD*CHN;
    short* FBh1 = FBh1raw + GUARD*CHN;
    short* FBl1 = FBl1raw + GUARD*CHN;
    float* outp = (float*)d_out;

    hipMemsetAsync(FR, 0, SZ_FR, stream);
    hipMemsetAsync(FBh0raw, 0, SZ_FB, stream);
    hipMemsetAsync(FBl0raw, 0, SZ_FB, stream);
    hipMemsetAsync(FBh1raw, 0, SZ_FB, stream);
    hipMemsetAsync(FBl1raw, 0, SZ_FB, stream);
    hipMemsetAsync(AT, 0, SZ_AT, stream);

    const int feat = BATCH*CHN*NSP;
    dim3 blk(256);

    k_prep_w<<<(NBLK*2*9*CHN*CHN + 255)/256, blk, 0, stream>>>(rw1, rw2, Whi, Wlo);
    k_prep_wqkv<<<(80*CHN + 255)/256, blk, 0, stream>>>(wq, wk, wv, Wqh, Wql);
    k_prep_wout<<<(81*CIN*CHN + 255)/256, blk, 0, stream>>>(w_out, Wo);
    k_conv_in<<<(feat + 255)/256, blk, 0, stream>>>(x, w_in, b_in, a_in, FR, FBh0, FBl0);
    for (int i = 0; i < NBLK; ++i) {
        k_conv3_mfma<<<BATCH*147, blk, 0, stream>>>(
            FBh0, FBl0,
            Whi + (size_t)(2*i)*9*CHN*CHN, Wlo + (size_t)(2*i)*9*CHN*CHN,
            rb1 + i*CHN, ra + i, (float*)nullptr, FBh1, FBl1, 0);
        k_conv3_mfma<<<BATCH*147, blk, 0, stream>>>(
            FBh1, FBl1,
            Whi + (size_t)(2*i+1)*9*CHN*CHN, Wlo + (size_t)(2*i+1)*9*CHN*CHN,
            rb2 + i*CHN, ra + i, FR, FBh0, FBl0, 1);
    }
    k_qkv_mfma<<<BATCH*147, blk, 0, stream>>>(
        FBh0, FBl0, Wqh, Wql, bq, bk, bv, Qb16, Kb16, Vb16);
    k_attn_mfma<<<BATCH*(NSP/16), dim3(128), 0, stream>>>(
        Qb16, Kb16, Vb16, FR, gamma, AT);
    k_conv_out<<<(BATCH*NSP)/16, blk, 0, stream>>>(AT, Wo, b_out, outp);
}

// Round 6
// 839.070 us; speedup vs baseline: 5.6662x; 1.1948x over previous
//
#include <hip/hip_runtime.h>
#include <cmath>

#define BATCH 2
#define CIN 3
#define HH 96
#define WW 96
#define NSP (HH*WW)      // 9216
#define CHN 64
#define C8 8
#define NBLK 5

#define PW 98            // padded width/height (3x3 convs)
#define PN (PW*PW)       // 9604 padded spatial
#define GUARD 128        // guard entries (spatial) each side of FB buffers
#define FBSTRIDE ((PN + 2*GUARD)*CHN)   // shorts per batch in FB buffers

#define PW2 104          // padded width for 9x9 conv_out input
#define PN2 (PW2*PW2)    // 10816

#define LOG2E 1.4426950408889634f

typedef __attribute__((ext_vector_type(8))) short bf16x8;
typedef __attribute__((ext_vector_type(4))) float f32x4;

static __device__ __forceinline__ short f2b(float f) {
    union { float f; unsigned u; } v; v.f = f;
    unsigned r = (v.u + 0x7FFFu + ((v.u >> 16) & 1u)) >> 16;
    return (short)r;
}
static __device__ __forceinline__ float b2f(short s) {
    union { unsigned u; float f; } v; v.u = ((unsigned)(unsigned short)s) << 16;
    return v.f;
}
static __device__ __forceinline__ void split2(float v, short& hi, short& lo) {
    hi = f2b(v);
    lo = f2b(v - b2f(hi));
}

// ---------------------------------------------------------------------------
// weight prep: rw[blk][co][ci][3][3] fp32 -> Whi/Wlo[conv][kyx][co][ci] bf16
__global__ __launch_bounds__(256) void k_prep_w(const float* __restrict__ rw1,
        const float* __restrict__ rw2, short* __restrict__ Whi,
        short* __restrict__ Wlo) {
    int idx = blockIdx.x * 256 + threadIdx.x;
    const int TOT = NBLK*2*9*CHN*CHN;
    if (idx >= TOT) return;
    int ci  = idx & 63;
    int co  = (idx >> 6) & 63;
    int kyx = (idx >> 12) % 9;
    int conv = idx / (9*CHN*CHN);
    int blk = conv >> 1, s = conv & 1;
    const float* src = s ? rw2 : rw1;
    float v = src[(((size_t)(blk*CHN + co))*CHN + ci)*9 + kyx];
    short h, l; split2(v, h, l);
    Whi[idx] = h; Wlo[idx] = l;
}

// qkv weight prep: -> Wq[co=0..79][ci] bf16 hi/lo (0-7 wq, 8-15 wk, 16-79 wv)
__global__ __launch_bounds__(256) void k_prep_wqkv(const float* __restrict__ wq,
        const float* __restrict__ wk, const float* __restrict__ wv,
        short* __restrict__ Wh, short* __restrict__ Wl) {
    int idx = blockIdx.x * 256 + threadIdx.x;
    if (idx >= 80*CHN) return;
    int ci = idx & 63, co = idx >> 6;
    float v;
    if (co < 8)       v = wq[co*CHN + ci];
    else if (co < 16) v = wk[(co-8)*CHN + ci];
    else              v = wv[(co-16)*CHN + ci];
    short h, l; split2(v, h, l);
    Wh[idx] = h; Wl[idx] = l;
}

// conv_out weight prep: w_out[co][ci][81] fp32 -> Wo[kyx][co][ci] fp32
__global__ __launch_bounds__(256) void k_prep_wout(const float* __restrict__ w_out,
        float* __restrict__ Wo) {
    int idx = blockIdx.x * 256 + threadIdx.x;
    if (idx >= 81*CIN*CHN) return;
    int ci = idx & 63;
    int co = (idx >> 6) % 3;
    int kyx = idx / 192;
    Wo[idx] = w_out[((size_t)(co*CHN + ci))*81 + kyx];
}

// ---------------------------------------------------------------------------
// conv 9x9 (3 -> 64), pad 4, + PReLU -> FR (fp32 n-major padded) + FBhi/FBlo
__global__ __launch_bounds__(256) void k_conv_in(const float* __restrict__ x,
        const float* __restrict__ w, const float* __restrict__ bias,
        const float* __restrict__ a, float* __restrict__ FR,
        short* __restrict__ FBhi, short* __restrict__ FBlo) {
    int idx = blockIdx.x * 256 + threadIdx.x;
    if (idx >= BATCH*CHN*NSP) return;
    int n  = idx % NSP;
    int co = (idx / NSP) % CHN;
    int b  = idx / (NSP*CHN);
    int y = n / WW, xx = n % WW;
    float sum = bias[co];
    int ky0 = max(0, 4 - y),  ky1 = min(9, 100 - y);
    int kx0 = max(0, 4 - xx), kx1 = min(9, 100 - xx);
    for (int ci = 0; ci < CIN; ++ci) {
        const float* xin = x + ((size_t)(b*CIN + ci))*NSP;
        const float* wp  = w + ((size_t)(co*CIN + ci))*81;
        for (int ky = ky0; ky < ky1; ++ky) {
            const float* row = xin + (y + ky - 4)*WW + (xx - 4);
            const float* wr  = wp + ky*9;
            for (int kx = kx0; kx < kx1; ++kx)
                sum = fmaf(row[kx], wr[kx], sum);
        }
    }
    float sl = a[0];
    float v = sum >= 0.f ? sum : sl*sum;
    int np = (y + 1)*PW + xx + 1;
    FR[((size_t)b*PN + np)*CHN + co] = v;
    short h, l; split2(v, h, l);
    FBhi[(size_t)b*FBSTRIDE + (size_t)np*CHN + co] = h;
    FBlo[(size_t)b*FBSTRIDE + (size_t)np*CHN + co] = l;
}

// ---------------------------------------------------------------------------
// 3x3 conv 64->64, implicit GEMM, split-bf16 3-MFMA (~fp32 precision).
// Wave = 16 spatial x 32 co (2 ct tiles). Block = 4 waves = 32 spatial x 64 co.
__global__ __launch_bounds__(256) void k_conv3_mfma(
        const short* __restrict__ FBhi_in, const short* __restrict__ FBlo_in,
        const short* __restrict__ Whi, const short* __restrict__ Wlo,
        const float* __restrict__ bias, const float* __restrict__ slope_p,
        float* __restrict__ FR,
        short* __restrict__ FBhi_out, short* __restrict__ FBlo_out, int mode) {
    int t = threadIdx.x;
    int w = t >> 6, lane = t & 63;
    int q = lane >> 4, n16 = lane & 15;
    int blk = blockIdx.x;
    int b = blk / 294, chunk = blk % 294;
    int nb = 98 + chunk*32 + (w >> 1)*16 + n16;
    int cth = (w & 1)*2;                 // this wave's ct tiles: cth, cth+1

    const short* fbh = FBhi_in + (size_t)b*FBSTRIDE;
    const short* fbl = FBlo_in + (size_t)b*FBSTRIDE;
    f32x4 acc[2] = {{0,0,0,0},{0,0,0,0}};

    int nbase = nb*CHN;
    #pragma unroll
    for (int kyx = 0; kyx < 9; ++kyx) {
        int dy = kyx/3 - 1, dx = kyx%3 - 1;
        int boff = nbase + (dy*PW + dx)*CHN;
        const short* wph = Whi + (size_t)kyx*CHN*CHN;
        const short* wpl = Wlo + (size_t)kyx*CHN*CHN;
        #pragma unroll
        for (int cih = 0; cih < 2; ++cih) {
            int xoff = boff + cih*32 + q*8;
            bf16x8 bhi = *(const bf16x8*)(fbh + xoff);
            bf16x8 blo = *(const bf16x8*)(fbl + xoff);
            #pragma unroll
            for (int ctl = 0; ctl < 2; ++ctl) {
                int aoff = ((cth + ctl)*16 + n16)*CHN + cih*32 + q*8;
                bf16x8 ahi = *(const bf16x8*)(wph + aoff);
                bf16x8 alo = *(const bf16x8*)(wpl + aoff);
                acc[ctl] = __builtin_amdgcn_mfma_f32_16x16x32_bf16(ahi, bhi, acc[ctl], 0, 0, 0);
                acc[ctl] = __builtin_amdgcn_mfma_f32_16x16x32_bf16(ahi, blo, acc[ctl], 0, 0, 0);
                acc[ctl] = __builtin_amdgcn_mfma_f32_16x16x32_bf16(alo, bhi, acc[ctl], 0, 0, 0);
            }
        }
    }

    int yy = nb / PW;
    int xx = nb - yy*PW;
    if (xx < 1 || xx > 96 || yy < 1 || yy > 96) return;
    float sl = slope_p[0];
    short* fboh = FBhi_out + (size_t)b*FBSTRIDE + (size_t)nb*CHN;
    short* fbol = FBlo_out + (size_t)b*FBSTRIDE + (size_t)nb*CHN;
    float* fr  = FR + ((size_t)b*PN + nb)*CHN;
    #pragma unroll
    for (int ctl = 0; ctl < 2; ++ctl) {
        #pragma unroll
        for (int r = 0; r < 4; ++r) {
            int co = (cth + ctl)*16 + q*4 + r;
            float v = acc[ctl][r] + bias[co];
            if (mode == 0) {
                v = v >= 0.f ? v : sl*v;
            } else {
                v += fr[co];
                fr[co] = v;
            }
            short h, l; split2(v, h, l);
            fboh[co] = h;
            fbol[co] = l;
        }
    }
}

// ---------------------------------------------------------------------------
// qkv projection as 1x1-conv implicit GEMM (80 outputs = 8 q + 8 k + 64 v).
// Q is pre-scaled by log2(e) so attention can use exp2.
__global__ __launch_bounds__(256) void k_qkv_mfma(
        const short* __restrict__ FBhi_in, const short* __restrict__ FBlo_in,
        const short* __restrict__ Wh, const short* __restrict__ Wl,
        const float* __restrict__ bq, const float* __restrict__ bk,
        const float* __restrict__ bv,
        short* __restrict__ Qb, short* __restrict__ Kb, short* __restrict__ Vb) {
    int t = threadIdx.x;
    int w = t >> 6, lane = t & 63;
    int q = lane >> 4, n16 = lane & 15;
    int blk = blockIdx.x;
    int b = blk / 147, chunk = blk % 147;
    int nb = 98 + chunk*64 + w*16 + n16;

    const short* fbh = FBhi_in + (size_t)b*FBSTRIDE;
    const short* fbl = FBlo_in + (size_t)b*FBSTRIDE;
    f32x4 acc[5] = {{0,0,0,0},{0,0,0,0},{0,0,0,0},{0,0,0,0},{0,0,0,0}};

    int nbase = nb*CHN;
    #pragma unroll
    for (int cih = 0; cih < 2; ++cih) {
        int xoff = nbase + cih*32 + q*8;
        bf16x8 bhi = *(const bf16x8*)(fbh + xoff);
        bf16x8 blo = *(const bf16x8*)(fbl + xoff);
        #pragma unroll
        for (int ct = 0; ct < 5; ++ct) {
            int aoff = (ct*16 + n16)*CHN + cih*32 + q*8;
            bf16x8 ahi = *(const bf16x8*)(Wh + aoff);
            bf16x8 alo = *(const bf16x8*)(Wl + aoff);
            acc[ct] = __builtin_amdgcn_mfma_f32_16x16x32_bf16(ahi, bhi, acc[ct], 0, 0, 0);
            acc[ct] = __builtin_amdgcn_mfma_f32_16x16x32_bf16(ahi, blo, acc[ct], 0, 0, 0);
            acc[ct] = __builtin_amdgcn_mfma_f32_16x16x32_bf16(alo, bhi, acc[ct], 0, 0, 0);
        }
    }

    int yy = nb / PW;
    int xx = nb - yy*PW;
    if (xx < 1 || xx > 96 || yy < 1 || yy > 96) return;
    int n = (yy - 1)*WW + (xx - 1);
    #pragma unroll
    for (int ct = 0; ct < 5; ++ct) {
        #pragma unroll
        for (int r = 0; r < 4; ++r) {
            int co = ct*16 + q*4 + r;
            float v = acc[ct][r];
            if (co < 8)
                Qb[((size_t)b*NSP + n)*8 + co] = f2b((v + bq[co]) * LOG2E);
            else if (co < 16)
                Kb[((size_t)b*NSP + n)*8 + (co-8)] = f2b(v + bk[co-8]);
            else
                Vb[((size_t)(b*CHN + co-16))*NSP + n] = f2b(v + bv[co-16]);
        }
    }
}

// ---------------------------------------------------------------------------
// Barrier-free MFMA flash attention.
// Block = 256 thr = 4 waves; block owns 32 q-rows (i0..i0+31); wave w handles
// j-quarter w (2304 j, 36 chunks of 64). Energy computed TRANSPOSED (A=K,
// B=Q -> D[j][i]) with a permuted j->tile map chosen so the P registers are
// already in PV A-fragment order (no LDS transpose, no barriers in the loop).
// Online softmax state is per-lane (i = n16): m, l scalars per row-group.
// Single __syncthreads before the 4-way j-merge in LDS.
__global__ __launch_bounds__(256) void k_attn_mfma(
        const short* __restrict__ Qb, const short* __restrict__ Kb,
        const short* __restrict__ Vb, const float* __restrict__ FR,
        const float* __restrict__ gamma_p, float* __restrict__ AT) {
    __shared__ float Opart[4][2][16][68];
    __shared__ float msh[4][2][16], lsh[4][2][16];

    int blk = blockIdx.x;
    int b  = blk / (NSP/32);
    int i0 = (blk % (NSP/32)) * 32;
    int t = threadIdx.x;
    int w = t >> 6;
    int lane = t & 63;
    int quad = lane >> 4, n16 = lane & 15;

    const short* Qp = Qb + ((size_t)b*NSP)*8;
    const short* Kp = Kb + ((size_t)b*NSP)*8;
    const short* Vp = Vb + ((size_t)b*CHN)*NSP;

    // Q fragments (B-operand): lane(quad,n16) holds Q[i0+rg*16+n16][ch quad*8..]
    bf16x8 qf[2];
    #pragma unroll
    for (int rg = 0; rg < 2; ++rg) {
        bf16x8 z = {0,0,0,0,0,0,0,0};
        qf[rg] = z;
        if (quad == 0)
            qf[rg] = *(const bf16x8*)(Qp + (size_t)(i0 + rg*16 + n16)*8);
    }

    f32x4 accO[2][4] = {{{0,0,0,0},{0,0,0,0},{0,0,0,0},{0,0,0,0}},
                        {{0,0,0,0},{0,0,0,0},{0,0,0,0},{0,0,0,0}}};
    float m[2]  = {-1e30f, -1e30f};
    float lp[2] = {0.f, 0.f};

    // permuted kf row offset within chunk for tile tt, lane n16:
    //   j = (tt>>1)*32 + (n16>>2)*8 + (tt&1)*4 + (n16&3)
    int krow_base = (n16 >> 2)*8 + (n16 & 3);

    for (int jc = 0; jc < 36; ++jc) {
        int j0 = w*2304 + jc*64;
        // ---- energy: D[j][i], 4 permuted tiles, 2 row-groups ----
        bf16x8 kf[4];
        #pragma unroll
        for (int tt = 0; tt < 4; ++tt) {
            bf16x8 z = {0,0,0,0,0,0,0,0};
            kf[tt] = z;
            if (quad == 0) {
                int jrow = j0 + (tt >> 1)*32 + (tt & 1)*4 + krow_base;
                kf[tt] = *(const bf16x8*)(Kp + (size_t)jrow*8);
            }
        }
        f32x4 e[2][4];
        #pragma unroll
        for (int rg = 0; rg < 2; ++rg)
            #pragma unroll
            for (int tt = 0; tt < 4; ++tt) {
                f32x4 z = {0.f,0.f,0.f,0.f};
                e[rg][tt] = __builtin_amdgcn_mfma_f32_16x16x32_bf16(kf[tt], qf[rg], z, 0, 0, 0);
            }
        // ---- online softmax (per-lane row i = n16) ----
        float alpha[2];
        #pragma unroll
        for (int rg = 0; rg < 2; ++rg) {
            float v = e[rg][0][0];
            #pragma unroll
            for (int tt = 0; tt < 4; ++tt)
                #pragma unroll
                for (int r = 0; r < 4; ++r)
                    v = fmaxf(v, e[rg][tt][r]);
            v = fmaxf(v, __shfl_xor(v, 16));
            v = fmaxf(v, __shfl_xor(v, 32));
            float mn = fmaxf(m[rg], v);
            alpha[rg] = exp2f(m[rg] - mn);
            m[rg] = mn;
            float s = 0.f;
            #pragma unroll
            for (int tt = 0; tt < 4; ++tt)
                #pragma unroll
                for (int r = 0; r < 4; ++r) {
                    float p = exp2f(e[rg][tt][r] - mn);
                    e[rg][tt][r] = p;
                    s += p;
                }
            lp[rg] = lp[rg]*alpha[rg] + s;
        }
        // rescale O accumulators: alpha for row q*4+r via lane gather
        #pragma unroll
        for (int rg = 0; rg < 2; ++rg) {
            #pragma unroll
            for (int r = 0; r < 4; ++r) {
                float ar = __shfl(alpha[rg], quad*4 + r);
                #pragma unroll
                for (int ct = 0; ct < 4; ++ct)
                    accO[rg][ct][r] *= ar;
            }
        }
        // ---- PV: pf comes straight from e registers (trunc-pack to bf16) ----
        #pragma unroll
        for (int ks = 0; ks < 2; ++ks) {
            bf16x8 vf[4];
            #pragma unroll
            for (int ct = 0; ct < 4; ++ct)
                vf[ct] = *(const bf16x8*)(Vp + (size_t)(ct*16 + n16)*NSP
                                          + j0 + ks*32 + quad*8);
            #pragma unroll
            for (int rg = 0; rg < 2; ++rg) {
                union { int di[4]; bf16x8 v8; } pu;
                int t2 = ks*2;
                pu.di[0] = __builtin_amdgcn_perm(__float_as_uint(e[rg][t2][1]),
                                                 __float_as_uint(e[rg][t2][0]), 0x07060302u);
                pu.di[1] = __builtin_amdgcn_perm(__float_as_uint(e[rg][t2][3]),
                                                 __float_as_uint(e[rg][t2][2]), 0x07060302u);
                pu.di[2] = __builtin_amdgcn_perm(__float_as_uint(e[rg][t2+1][1]),
                                                 __float_as_uint(e[rg][t2+1][0]), 0x07060302u);
                pu.di[3] = __builtin_amdgcn_perm(__float_as_uint(e[rg][t2+1][3]),
                                                 __float_as_uint(e[rg][t2+1][2]), 0x07060302u);
                #pragma unroll
                for (int ct = 0; ct < 4; ++ct)
                    accO[rg][ct] = __builtin_amdgcn_mfma_f32_16x16x32_bf16(
                        pu.v8, vf[ct], accO[rg][ct], 0, 0, 0);
            }
        }
    }

    // ---- write per-wave partials ----
    #pragma unroll
    for (int rg = 0; rg < 2; ++rg) {
        float l = lp[rg];
        l += __shfl_xor(l, 16);
        l += __shfl_xor(l, 32);
        if (quad == 0) {
            msh[w][rg][n16] = m[rg];
            lsh[w][rg][n16] = l;
        }
        #pragma unroll
        for (int ct = 0; ct < 4; ++ct)
            #pragma unroll
            for (int r = 0; r < 4; ++r)
                Opart[w][rg][quad*4 + r][ct*16 + n16] = accO[rg][ct][r];
    }
    __syncthreads();

    // ---- 4-way j-merge + residual + store (thread t: row t>>3, 8 cols) ----
    float g = gamma_p[0];
    int row = t >> 3;            // 0..31
    int rg = row >> 4, ii = row & 15;
    int c0 = (t & 7)*8;
    float mm = fmaxf(fmaxf(msh[0][rg][ii], msh[1][rg][ii]),
                     fmaxf(msh[2][rg][ii], msh[3][rg][ii]));
    float sc[4], ll = 0.f;
    #pragma unroll
    for (int ww = 0; ww < 4; ++ww) {
        sc[ww] = exp2f(msh[ww][rg][ii] - mm);
        ll += sc[ww]*lsh[ww][rg][ii];
    }
    float inv = g / ll;
    int gi = i0 + row;
    int iy = gi / WW, ix = gi - iy*WW;
    size_t frb = ((size_t)b*PN + (iy + 1)*PW + ix + 1)*CHN;
    size_t atb = ((size_t)b*PN2 + (iy + 4)*PW2 + ix + 4)*CHN;
    #pragma unroll
    for (int cc = 0; cc < 8; ++cc) {
        int c = c0 + cc;
        float Ov = sc[0]*Opart[0][rg][ii][c] + sc[1]*Opart[1][rg][ii][c]
                 + sc[2]*Opart[2][rg][ii][c] + sc[3]*Opart[3][rg][ii][c];
        AT[atb + c] = Ov*inv + FR[frb + c];
    }
}

// ---------------------------------------------------------------------------
// conv 9x9 (64 -> 3) + tanh. Wave per 4 pixels, lane = ci, input n-major
// zero-padded AT[b][104*104][64]; transposed weights Wo[kyx][co][ci].
__global__ __launch_bounds__(256) void k_conv_out(const float* __restrict__ AT,
        const float* __restrict__ Wo, const float* __restrict__ bias,
        float* __restrict__ out) {
    int t = threadIdx.x;
    int w = t >> 6, lane = t & 63;
    int base = blockIdx.x*16 + w*4;       // 4 consecutive pixels, same row
    int b = base / NSP;
    int n0 = base % NSP;
    int y0 = n0 / WW, x0 = n0 % WW;       // x0 % 4 == 0, so x0+3 <= 95

    float s[4][3] = {{0,0,0},{0,0,0},{0,0,0},{0,0,0}};
    for (int ky = 0; ky < 9; ++ky) {
        const float* arow = AT + ((size_t)b*PN2 + (size_t)(y0 + ky)*PW2 + x0)*CHN + lane;
        const float* wrow = Wo + (size_t)ky*9*192;
        float xv[12];
        #pragma unroll
        for (int u = 0; u < 12; ++u)
            xv[u] = arow[(size_t)u*CHN];
        #pragma unroll
        for (int kx = 0; kx < 9; ++kx) {
            float w0 = wrow[kx*192 +   0 + lane];
            float w1 = wrow[kx*192 +  64 + lane];
            float w2 = wrow[kx*192 + 128 + lane];
            #pragma unroll
            for (int p = 0; p < 4; ++p) {
                float x = xv[kx + p];
                s[p][0] = fmaf(x, w0, s[p][0]);
                s[p][1] = fmaf(x, w1, s[p][1]);
                s[p][2] = fmaf(x, w2, s[p][2]);
            }
        }
    }
    #pragma unroll
    for (int p = 0; p < 4; ++p)
        #pragma unroll
        for (int c = 0; c < 3; ++c) {
            float v = s[p][c];
            v += __shfl_xor(v, 1);
            v += __shfl_xor(v, 2);
            v += __shfl_xor(v, 4);
            v += __shfl_xor(v, 8);
            v += __shfl_xor(v, 16);
            v += __shfl_xor(v, 32);
            s[p][c] = v;
        }
    #pragma unroll
    for (int p = 0; p < 4; ++p)
        #pragma unroll
        for (int c = 0; c < 3; ++c)
            if (lane == p*3 + c)
                out[((size_t)(b*3 + c))*NSP + n0 + p] = tanhf(s[p][c] + bias[c]);
}

// ---------------------------------------------------------------------------
extern "C" void kernel_launch(void* const* d_in, const int* in_sizes, int n_in,
                              void* d_out, int out_size, void* d_ws, size_t ws_size,
                              hipStream_t stream) {
    (void)in_sizes; (void)n_in; (void)out_size; (void)ws_size;
    const float* x     = (const float*)d_in[0];
    const float* w_in  = (const float*)d_in[1];
    const float* b_in  = (const float*)d_in[2];
    const float* a_in  = (const float*)d_in[3];
    const float* rw1   = (const float*)d_in[4];
    const float* rb1   = (const float*)d_in[5];
    const float* ra    = (const float*)d_in[6];
    const float* rw2   = (const float*)d_in[7];
    const float* rb2   = (const float*)d_in[8];
    const float* wq    = (const float*)d_in[9];
    const float* bq    = (const float*)d_in[10];
    const float* wk    = (const float*)d_in[11];
    const float* bk    = (const float*)d_in[12];
    const float* wv    = (const float*)d_in[13];
    const float* bv    = (const float*)d_in[14];
    const float* gamma = (const float*)d_in[15];
    const float* w_out = (const float*)d_in[16];
    const float* b_out = (const float*)d_in[17];

    // workspace layout (bytes), all chunks 16B-aligned
    const size_t SZ_FR  = (size_t)BATCH*PN*CHN*4;        // 4,917,248
    const size_t SZ_FB  = (size_t)BATCH*FBSTRIDE*2;      // 2,524,160
    const size_t SZ_WT  = (size_t)NBLK*2*9*CHN*CHN*2;    //   737,280
    const size_t SZ_QK  = (size_t)BATCH*NSP*C8*2;        //   294,912
    const size_t SZ_VB  = (size_t)BATCH*CHN*NSP*2;       // 2,359,296
    const size_t SZ_AT  = (size_t)BATCH*PN2*CHN*4;       // 5,537,792
    const size_t SZ_WO  = (size_t)81*CIN*CHN*4;          //    62,208
    const size_t SZ_WQ  = (size_t)80*CHN*2;              //    10,240
    char* p = (char*)d_ws;
    float* FR      = (float*)p;           p += SZ_FR;
    short* FBh0raw = (short*)p;           p += SZ_FB;
    short* FBl0raw = (short*)p;           p += SZ_FB;
    short* FBh1raw = (short*)p;           p += SZ_FB;
    short* FBl1raw = (short*)p;           p += SZ_FB;
    short* Whi     = (short*)p;           p += SZ_WT;
    short* Wlo     = (short*)p;           p += SZ_WT;
    short* Qb16    = (short*)p;           p += SZ_QK;
    short* Kb16    = (short*)p;           p += SZ_QK;
    short* Vb16    = (short*)p;           p += SZ_VB;
    float* AT      = (float*)p;           p += SZ_AT;
    float* Wo      = (float*)p;           p += SZ_WO;
    short* Wqh     = (short*)p;           p += SZ_WQ;
    short* Wql     = (short*)p;           p += SZ_WQ;
    short* FBh0 = FBh0raw + GUARD*CHN;
    short* FBl0 = FBl0raw + GUARD*CHN;
    short* FBh1 = FBh1raw + GUARD*CHN;
    short* FBl1 = FBl1raw + GUARD*CHN;
    float* outp = (float*)d_out;

    hipMemsetAsync(FR, 0, SZ_FR, stream);
    hipMemsetAsync(FBh0raw, 0, SZ_FB, stream);
    hipMemsetAsync(FBl0raw, 0, SZ_FB, stream);
    hipMemsetAsync(FBh1raw, 0, SZ_FB, stream);
    hipMemsetAsync(FBl1raw, 0, SZ_FB, stream);
    hipMemsetAsync(AT, 0, SZ_AT, stream);

    const int feat = BATCH*CHN*NSP;
    dim3 blk(256);

    k_prep_w<<<(NBLK*2*9*CHN*CHN + 255)/256, blk, 0, stream>>>(rw1, rw2, Whi, Wlo);
    k_prep_wqkv<<<(80*CHN + 255)/256, blk, 0, stream>>>(wq, wk, wv, Wqh, Wql);
    k_prep_wout<<<(81*CIN*CHN + 255)/256, blk, 0, stream>>>(w_out, Wo);
    k_conv_in<<<(feat + 255)/256, blk, 0, stream>>>(x, w_in, b_in, a_in, FR, FBh0, FBl0);
    for (int i = 0; i < NBLK; ++i) {
        k_conv3_mfma<<<BATCH*294, blk, 0, stream>>>(
            FBh0, FBl0,
            Whi + (size_t)(2*i)*9*CHN*CHN, Wlo + (size_t)(2*i)*9*CHN*CHN,
            rb1 + i*CHN, ra + i, (float*)nullptr, FBh1, FBl1, 0);
        k_conv3_mfma<<<BATCH*294, blk, 0, stream>>>(
            FBh1, FBl1,
            Whi + (size_t)(2*i+1)*9*CHN*CHN, Wlo + (size_t)(2*i+1)*9*CHN*CHN,
            rb2 + i*CHN, ra + i, FR, FBh0, FBl0, 1);
    }
    k_qkv_mfma<<<BATCH*147, blk, 0, stream>>>(
        FBh0, FBl0, Wqh, Wql, bq, bk, bv, Qb16, Kb16, Vb16);
    k_attn_mfma<<<BATCH*(NSP/32), blk, 0, stream>>>(
        Qb16, Kb16, Vb16, FR, gamma, AT);
    k_conv_out<<<(BATCH*NSP)/16, blk, 0, stream>>>(AT, Wo, b_out, outp);
}

// Round 8
// 830.489 us; speedup vs baseline: 5.7247x; 1.0103x over previous
//
#include <hip/hip_runtime.h>
#include <cmath>

#define BATCH 2
#define CIN 3
#define HH 96
#define WW 96
#define NSP (HH*WW)      // 9216
#define CHN 64
#define C8 8
#define NBLK 5

#define PW 98            // padded width/height (3x3 convs)
#define PN (PW*PW)       // 9604 padded spatial
#define GUARD 128        // guard rows (spatial) each side of FBI buffers
#define FBST ((PN + 2*GUARD)*128)  // shorts per batch in FBI (hi|lo interleaved)

#define PW2 104          // padded width for 9x9 conv_out input
#define PN2 (PW2*PW2)    // 10816

#define LOG2E 1.4426950408889634f
#define BOOST 100.0f     // exponent boost: p' = 2^(e-M+BOOST), overflow-safe

typedef __attribute__((ext_vector_type(8))) short bf16x8;
typedef __attribute__((ext_vector_type(4))) float f32x4;

static __device__ __forceinline__ short f2b(float f) {
    union { float f; unsigned u; } v; v.f = f;
    unsigned r = (v.u + 0x7FFFu + ((v.u >> 16) & 1u)) >> 16;
    return (short)r;
}
static __device__ __forceinline__ float b2f(short s) {
    union { unsigned u; float f; } v; v.u = ((unsigned)(unsigned short)s) << 16;
    return v.f;
}
static __device__ __forceinline__ void split2(float v, short& hi, short& lo) {
    hi = f2b(v);
    lo = f2b(v - b2f(hi));
}

// ---------------------------------------------------------------------------
// weight prep: rw[blk][co][ci][3][3] fp32 -> Whi/Wlo[conv][kyx][co][ci] bf16
__global__ __launch_bounds__(256) void k_prep_w(const float* __restrict__ rw1,
        const float* __restrict__ rw2, short* __restrict__ Whi,
        short* __restrict__ Wlo) {
    int idx = blockIdx.x * 256 + threadIdx.x;
    const int TOT = NBLK*2*9*CHN*CHN;
    if (idx >= TOT) return;
    int ci  = idx & 63;
    int co  = (idx >> 6) & 63;
    int kyx = (idx >> 12) % 9;
    int conv = idx / (9*CHN*CHN);
    int blk = conv >> 1, s = conv & 1;
    const float* src = s ? rw2 : rw1;
    float v = src[(((size_t)(blk*CHN + co))*CHN + ci)*9 + kyx];
    short h, l; split2(v, h, l);
    Whi[idx] = h; Wlo[idx] = l;
}

// qkv weight prep: -> Wq[co=0..79][ci] bf16 hi/lo (0-7 wq, 8-15 wk, 16-79 wv)
__global__ __launch_bounds__(256) void k_prep_wqkv(const float* __restrict__ wq,
        const float* __restrict__ wk, const float* __restrict__ wv,
        short* __restrict__ Wh, short* __restrict__ Wl) {
    int idx = blockIdx.x * 256 + threadIdx.x;
    if (idx >= 80*CHN) return;
    int ci = idx & 63, co = idx >> 6;
    float v;
    if (co < 8)       v = wq[co*CHN + ci];
    else if (co < 16) v = wk[(co-8)*CHN + ci];
    else              v = wv[(co-16)*CHN + ci];
    short h, l; split2(v, h, l);
    Wh[idx] = h; Wl[idx] = l;
}

// conv_out weight prep: w_out[co][ci][81] fp32 -> Wo[kyx][co][ci] fp32
__global__ __launch_bounds__(256) void k_prep_wout(const float* __restrict__ w_out,
        float* __restrict__ Wo) {
    int idx = blockIdx.x * 256 + threadIdx.x;
    if (idx >= 81*CIN*CHN) return;
    int ci = idx & 63;
    int co = (idx >> 6) % 3;
    int kyx = idx / 192;
    Wo[idx] = w_out[((size_t)(co*CHN + ci))*81 + kyx];
}

// ---------------------------------------------------------------------------
// conv 9x9 (3 -> 64), pad 4, + PReLU -> FR (fp32 n-major padded) + FBI
__global__ __launch_bounds__(256) void k_conv_in(const float* __restrict__ x,
        const float* __restrict__ w, const float* __restrict__ bias,
        const float* __restrict__ a, float* __restrict__ FR,
        short* __restrict__ FBI) {
    int idx = blockIdx.x * 256 + threadIdx.x;
    if (idx >= BATCH*CHN*NSP) return;
    int n  = idx % NSP;
    int co = (idx / NSP) % CHN;
    int b  = idx / (NSP*CHN);
    int y = n / WW, xx = n % WW;
    float sum = bias[co];
    int ky0 = max(0, 4 - y),  ky1 = min(9, 100 - y);
    int kx0 = max(0, 4 - xx), kx1 = min(9, 100 - xx);
    for (int ci = 0; ci < CIN; ++ci) {
        const float* xin = x + ((size_t)(b*CIN + ci))*NSP;
        const float* wp  = w + ((size_t)(co*CIN + ci))*81;
        for (int ky = ky0; ky < ky1; ++ky) {
            const float* row = xin + (y + ky - 4)*WW + (xx - 4);
            const float* wr  = wp + ky*9;
            for (int kx = kx0; kx < kx1; ++kx)
                sum = fmaf(row[kx], wr[kx], sum);
        }
    }
    float sl = a[0];
    float v = sum >= 0.f ? sum : sl*sum;
    int np = (y + 1)*PW + xx + 1;
    FR[((size_t)b*PN + np)*CHN + co] = v;
    short h, l; split2(v, h, l);
    FBI[(size_t)b*FBST + (size_t)np*128 + co]      = h;
    FBI[(size_t)b*FBST + (size_t)np*128 + 64 + co] = l;
}

// ---------------------------------------------------------------------------
// 3x3 conv 64->64, implicit GEMM, split-bf16 3-MFMA, LDS-staged activations.
// Block = 32 spatial x 64 co; stages [nb0-99, nb0+131) x 256B into LDS once,
// then all 9 taps are ds_read_b128 (stride 136 shorts -> 2-way-free banks).
__global__ __launch_bounds__(256) void k_conv3_mfma(
        const short* __restrict__ FBin,
        const short* __restrict__ Whi, const short* __restrict__ Wlo,
        const float* __restrict__ bias, const float* __restrict__ slope_p,
        float* __restrict__ FR, short* __restrict__ FBout, int mode) {
    __shared__ short xs[230*136];    // 62,560 B
    int t = threadIdx.x;
    int w = t >> 6, lane = t & 63;
    int q = lane >> 4, n16 = lane & 15;
    int blk = blockIdx.x;
    int b = blk / 294, chunk = blk % 294;
    int nb0 = 98 + chunk*32;

    const short* src = FBin + (size_t)b*FBST + (size_t)(nb0 - 99)*128;
    #pragma unroll
    for (int k = 0; k < 15; ++k) {
        int u = k*256 + t;
        if (u < 3680) {
            int np = u >> 4, wi = u & 15;
            *(float4*)&xs[np*136 + wi*8] = *(const float4*)(src + (size_t)u*8);
        }
    }
    __syncthreads();

    int nb = nb0 + (w >> 1)*16 + n16;
    int cth = (w & 1)*2;                 // this wave's ct tiles: cth, cth+1
    f32x4 acc[2] = {{0,0,0,0},{0,0,0,0}};
    int lb0 = (99 + (w >> 1)*16 + n16)*136;

    #pragma unroll
    for (int kyx = 0; kyx < 9; ++kyx) {
        int dy = kyx/3 - 1, dx = kyx%3 - 1;
        int lb = lb0 + (dy*PW + dx)*136;
        const short* wph = Whi + (size_t)kyx*CHN*CHN;
        const short* wpl = Wlo + (size_t)kyx*CHN*CHN;
        #pragma unroll
        for (int cih = 0; cih < 2; ++cih) {
            bf16x8 bhi = *(const bf16x8*)&xs[lb + cih*32 + q*8];
            bf16x8 blo = *(const bf16x8*)&xs[lb + 64 + cih*32 + q*8];
            #pragma unroll
            for (int ctl = 0; ctl < 2; ++ctl) {
                int aoff = ((cth + ctl)*16 + n16)*CHN + cih*32 + q*8;
                bf16x8 ahi = *(const bf16x8*)(wph + aoff);
                bf16x8 alo = *(const bf16x8*)(wpl + aoff);
                acc[ctl] = __builtin_amdgcn_mfma_f32_16x16x32_bf16(ahi, bhi, acc[ctl], 0, 0, 0);
                acc[ctl] = __builtin_amdgcn_mfma_f32_16x16x32_bf16(ahi, blo, acc[ctl], 0, 0, 0);
                acc[ctl] = __builtin_amdgcn_mfma_f32_16x16x32_bf16(alo, bhi, acc[ctl], 0, 0, 0);
            }
        }
    }

    int yy = nb / PW;
    int xx = nb - yy*PW;
    if (xx < 1 || xx > 96 || yy < 1 || yy > 96) return;
    float sl = slope_p[0];
    short* fbo = FBout + (size_t)b*FBST + (size_t)nb*128;
    float* fr  = FR + ((size_t)b*PN + nb)*CHN;
    #pragma unroll
    for (int ctl = 0; ctl < 2; ++ctl) {
        #pragma unroll
        for (int r = 0; r < 4; ++r) {
            int co = (cth + ctl)*16 + q*4 + r;
            float v = acc[ctl][r] + bias[co];
            if (mode == 0) {
                v = v >= 0.f ? v : sl*v;
            } else {
                v += fr[co];
                fr[co] = v;
            }
            short h, l; split2(v, h, l);
            fbo[co]      = h;
            fbo[64 + co] = l;
        }
    }
}

// ---------------------------------------------------------------------------
// qkv projection as 1x1-conv implicit GEMM (80 outputs = 8 q + 8 k + 64 v).
// Q pre-scaled by log2(e). Also computes per-channel Kinf[c] = max_j |k_cj|.
__global__ __launch_bounds__(256) void k_qkv_mfma(
        const short* __restrict__ FBin,
        const short* __restrict__ Wh, const short* __restrict__ Wl,
        const float* __restrict__ bq, const float* __restrict__ bk,
        const float* __restrict__ bv,
        short* __restrict__ Qb, short* __restrict__ Kb, short* __restrict__ Vb,
        float* __restrict__ Kinf) {
    int t = threadIdx.x;
    int w = t >> 6, lane = t & 63;
    int q = lane >> 4, n16 = lane & 15;
    int blk = blockIdx.x;
    int b = blk / 147, chunk = blk % 147;
    int nb = 98 + chunk*64 + w*16 + n16;

    const short* fb = FBin + (size_t)b*FBST;
    f32x4 acc[5] = {{0,0,0,0},{0,0,0,0},{0,0,0,0},{0,0,0,0},{0,0,0,0}};

    int nbase = nb*128;
    #pragma unroll
    for (int cih = 0; cih < 2; ++cih) {
        bf16x8 bhi = *(const bf16x8*)(fb + nbase + cih*32 + q*8);
        bf16x8 blo = *(const bf16x8*)(fb + nbase + 64 + cih*32 + q*8);
        #pragma unroll
        for (int ct = 0; ct < 5; ++ct) {
            int aoff = (ct*16 + n16)*CHN + cih*32 + q*8;
            bf16x8 ahi = *(const bf16x8*)(Wh + aoff);
            bf16x8 alo = *(const bf16x8*)(Wl + aoff);
            acc[ct] = __builtin_amdgcn_mfma_f32_16x16x32_bf16(ahi, bhi, acc[ct], 0, 0, 0);
            acc[ct] = __builtin_amdgcn_mfma_f32_16x16x32_bf16(ahi, blo, acc[ct], 0, 0, 0);
            acc[ct] = __builtin_amdgcn_mfma_f32_16x16x32_bf16(alo, bhi, acc[ct], 0, 0, 0);
        }
    }

    int yy = nb / PW;
    int xx = nb - yy*PW;
    float kabs[4] = {0.f, 0.f, 0.f, 0.f};   // |k| for channel (q-2)*4+r, q>=2
    if (xx >= 1 && xx <= 96 && yy >= 1 && yy <= 96) {
        int n = (yy - 1)*WW + (xx - 1);
        #pragma unroll
        for (int ct = 0; ct < 5; ++ct) {
            #pragma unroll
            for (int r = 0; r < 4; ++r) {
                int co = ct*16 + q*4 + r;
                float v = acc[ct][r];
                if (co < 8)
                    Qb[((size_t)b*NSP + n)*8 + co] = f2b((v + bq[co]) * LOG2E);
                else if (co < 16) {
                    float kv = v + bk[co-8];
                    kabs[r] = fabsf(kv) * 1.01f;   // cover bf16 store rounding
                    Kb[((size_t)b*NSP + n)*8 + (co-8)] = f2b(kv);
                } else
                    Vb[((size_t)(b*CHN + co-16))*NSP + n] = f2b(v + bv[co-16]);
            }
        }
    }
    // per-channel k-max: reduce across n16 (xor masks stay within quad)
    #pragma unroll
    for (int r = 0; r < 4; ++r) {
        #pragma unroll
        for (int off = 1; off < 16; off <<= 1)
            kabs[r] = fmaxf(kabs[r], __shfl_xor(kabs[r], off));
    }
    if (q >= 2 && n16 == 0) {
        #pragma unroll
        for (int r = 0; r < 4; ++r)
            atomicMax((int*)&Kinf[(q - 2)*4 + r], __float_as_int(kabs[r]));
    }
}

// ---------------------------------------------------------------------------
// MFMA flash attention with BOUND-based softmax (no online max/rescale):
// M_i = sum_c |q_c| * Kinf[c] >= max_j e_ij (q already log2e-scaled); boost
// by 2^BOOST so a loose bound cannot flush the whole row to zero. Loop =
// MFMA + exp2 + l-adds only. M identical across waves -> merge is plain sum.
__global__ __launch_bounds__(256) void k_attn_mfma(
        const short* __restrict__ Qb, const short* __restrict__ Kb,
        const short* __restrict__ Vb, const float* __restrict__ FR,
        const float* __restrict__ gamma_p, const float* __restrict__ Kinf_p,
        float* __restrict__ AT) {
    __shared__ float Opart[4][2][16][68];
    __shared__ float lsh[4][2][16];

    int blk = blockIdx.x;
    int b  = blk / (NSP/32);
    int i0 = (blk % (NSP/32)) * 32;
    int t = threadIdx.x;
    int w = t >> 6;
    int lane = t & 63;
    int quad = lane >> 4, n16 = lane & 15;

    const short* Qp = Qb + ((size_t)b*NSP)*8;
    const short* Kp = Kb + ((size_t)b*NSP)*8;
    const short* Vp = Vb + ((size_t)b*CHN)*NSP;

    // Q fragments (B-operand) + per-row softmax bound M (boosted)
    bf16x8 qf[2];
    float Mi[2];
    #pragma unroll
    for (int rg = 0; rg < 2; ++rg) {
        bf16x8 z = {0,0,0,0,0,0,0,0};
        qf[rg] = z;
        if (quad == 0)
            qf[rg] = *(const bf16x8*)(Qp + (size_t)(i0 + rg*16 + n16)*8);
        float s1 = 0.f;
        #pragma unroll
        for (int c = 0; c < 8; ++c)
            s1 += fabsf(b2f(qf[rg][c])) * Kinf_p[c];
        float Mv = s1 + 1.0f - BOOST;
        Mi[rg] = __shfl(Mv, n16);      // broadcast row n16's bound to all quads
    }

    f32x4 accO[2][4] = {{{0,0,0,0},{0,0,0,0},{0,0,0,0},{0,0,0,0}},
                        {{0,0,0,0},{0,0,0,0},{0,0,0,0},{0,0,0,0}}};
    float lp[2] = {0.f, 0.f};

    // permuted kf row offset: j = (tt>>1)*32 + (n16>>2)*8 + (tt&1)*4 + (n16&3)
    int krow_base = (n16 >> 2)*8 + (n16 & 3);

    for (int jc = 0; jc < 36; ++jc) {
        int j0 = w*2304 + jc*64;
        bf16x8 kf[4];
        #pragma unroll
        for (int tt = 0; tt < 4; ++tt) {
            bf16x8 z = {0,0,0,0,0,0,0,0};
            kf[tt] = z;
            if (quad == 0) {
                int jrow = j0 + (tt >> 1)*32 + (tt & 1)*4 + krow_base;
                kf[tt] = *(const bf16x8*)(Kp + (size_t)jrow*8);
            }
        }
        f32x4 e[2][4];
        #pragma unroll
        for (int rg = 0; rg < 2; ++rg)
            #pragma unroll
            for (int tt = 0; tt < 4; ++tt) {
                f32x4 z = {0.f,0.f,0.f,0.f};
                e[rg][tt] = __builtin_amdgcn_mfma_f32_16x16x32_bf16(kf[tt], qf[rg], z, 0, 0, 0);
            }
        // p' = exp2(e - M + BOOST), accumulate l — no max tracking, no rescale
        #pragma unroll
        for (int rg = 0; rg < 2; ++rg) {
            float s = 0.f;
            #pragma unroll
            for (int tt = 0; tt < 4; ++tt)
                #pragma unroll
                for (int r = 0; r < 4; ++r) {
                    float p = exp2f(e[rg][tt][r] - Mi[rg]);
                    e[rg][tt][r] = p;
                    s += p;
                }
            lp[rg] += s;
        }
        // PV: pf straight from e registers (trunc-pack to bf16)
        #pragma unroll
        for (int ks = 0; ks < 2; ++ks) {
            bf16x8 vf[4];
            #pragma unroll
            for (int ct = 0; ct < 4; ++ct)
                vf[ct] = *(const bf16x8*)(Vp + (size_t)(ct*16 + n16)*NSP
                                          + j0 + ks*32 + quad*8);
            #pragma unroll
            for (int rg = 0; rg < 2; ++rg) {
                union { int di[4]; bf16x8 v8; } pu;
                int t2 = ks*2;
                pu.di[0] = __builtin_amdgcn_perm(__float_as_uint(e[rg][t2][1]),
                                                 __float_as_uint(e[rg][t2][0]), 0x07060302u);
                pu.di[1] = __builtin_amdgcn_perm(__float_as_uint(e[rg][t2][3]),
                                                 __float_as_uint(e[rg][t2][2]), 0x07060302u);
                pu.di[2] = __builtin_amdgcn_perm(__float_as_uint(e[rg][t2+1][1]),
                                                 __float_as_uint(e[rg][t2+1][0]), 0x07060302u);
                pu.di[3] = __builtin_amdgcn_perm(__float_as_uint(e[rg][t2+1][3]),
                                                 __float_as_uint(e[rg][t2+1][2]), 0x07060302u);
                #pragma unroll
                for (int ct = 0; ct < 4; ++ct)
                    accO[rg][ct] = __builtin_amdgcn_mfma_f32_16x16x32_bf16(
                        pu.v8, vf[ct], accO[rg][ct], 0, 0, 0);
            }
        }
    }

    // per-wave partials
    #pragma unroll
    for (int rg = 0; rg < 2; ++rg) {
        float l = lp[rg];
        l += __shfl_xor(l, 16);
        l += __shfl_xor(l, 32);
        if (quad == 0) lsh[w][rg][n16] = l;
        #pragma unroll
        for (int ct = 0; ct < 4; ++ct)
            #pragma unroll
            for (int r = 0; r < 4; ++r)
                Opart[w][rg][quad*4 + r][ct*16 + n16] = accO[rg][ct][r];
    }
    __syncthreads();

    // 4-way j-merge (plain sums; M identical) + residual + store
    float g = gamma_p[0];
    int row = t >> 3;            // 0..31
    int rg = row >> 4, ii = row & 15;
    int c0 = (t & 7)*8;
    float ll = lsh[0][rg][ii] + lsh[1][rg][ii] + lsh[2][rg][ii] + lsh[3][rg][ii];
    float inv = g / fmaxf(ll, 1e-35f);   // never NaN, worst case local fallback
    int gi = i0 + row;
    int iy = gi / WW, ix = gi - iy*WW;
    size_t frb = ((size_t)b*PN + (iy + 1)*PW + ix + 1)*CHN;
    size_t atb = ((size_t)b*PN2 + (iy + 4)*PW2 + ix + 4)*CHN;
    #pragma unroll
    for (int cc = 0; cc < 8; ++cc) {
        int c = c0 + cc;
        float Ov = Opart[0][rg][ii][c] + Opart[1][rg][ii][c]
                 + Opart[2][rg][ii][c] + Opart[3][rg][ii][c];
        AT[atb + c] = Ov*inv + FR[frb + c];
    }
}

// ---------------------------------------------------------------------------
// conv 9x9 (64 -> 3) + tanh. Wave per 4 pixels, lane = ci.
__global__ __launch_bounds__(256) void k_conv_out(const float* __restrict__ AT,
        const float* __restrict__ Wo, const float* __restrict__ bias,
        float* __restrict__ out) {
    int t = threadIdx.x;
    int w = t >> 6, lane = t & 63;
    int base = blockIdx.x*16 + w*4;
    int b = base / NSP;
    int n0 = base % NSP;
    int y0 = n0 / WW, x0 = n0 % WW;

    float s[4][3] = {{0,0,0},{0,0,0},{0,0,0},{0,0,0}};
    for (int ky = 0; ky < 9; ++ky) {
        const float* arow = AT + ((size_t)b*PN2 + (size_t)(y0 + ky)*PW2 + x0)*CHN + lane;
        const float* wrow = Wo + (size_t)ky*9*192;
        float xv[12];
        #pragma unroll
        for (int u = 0; u < 12; ++u)
            xv[u] = arow[(size_t)u*CHN];
        #pragma unroll
        for (int kx = 0; kx < 9; ++kx) {
            float w0 = wrow[kx*192 +   0 + lane];
            float w1 = wrow[kx*192 +  64 + lane];
            float w2 = wrow[kx*192 + 128 + lane];
            #pragma unroll
            for (int p = 0; p < 4; ++p) {
                float x = xv[kx + p];
                s[p][0] = fmaf(x, w0, s[p][0]);
                s[p][1] = fmaf(x, w1, s[p][1]);
                s[p][2] = fmaf(x, w2, s[p][2]);
            }
        }
    }
    #pragma unroll
    for (int p = 0; p < 4; ++p)
        #pragma unroll
        for (int c = 0; c < 3; ++c) {
            float v = s[p][c];
            v += __shfl_xor(v, 1);
            v += __shfl_xor(v, 2);
            v += __shfl_xor(v, 4);
            v += __shfl_xor(v, 8);
            v += __shfl_xor(v, 16);
            v += __shfl_xor(v, 32);
            s[p][c] = v;
        }
    #pragma unroll
    for (int p = 0; p < 4; ++p)
        #pragma unroll
        for (int c = 0; c < 3; ++c)
            if (lane == p*3 + c)
                out[((size_t)(b*3 + c))*NSP + n0 + p] = tanhf(s[p][c] + bias[c]);
}

// ---------------------------------------------------------------------------
extern "C" void kernel_launch(void* const* d_in, const int* in_sizes, int n_in,
                              void* d_out, int out_size, void* d_ws, size_t ws_size,
                              hipStream_t stream) {
    (void)in_sizes; (void)n_in; (void)out_size; (void)ws_size;
    const float* x     = (const float*)d_in[0];
    const float* w_in  = (const float*)d_in[1];
    const float* b_in  = (const float*)d_in[2];
    const float* a_in  = (const float*)d_in[3];
    const float* rw1   = (const float*)d_in[4];
    const float* rb1   = (const float*)d_in[5];
    const float* ra    = (const float*)d_in[6];
    const float* rw2   = (const float*)d_in[7];
    const float* rb2   = (const float*)d_in[8];
    const float* wq    = (const float*)d_in[9];
    const float* bq    = (const float*)d_in[10];
    const float* wk    = (const float*)d_in[11];
    const float* bk    = (const float*)d_in[12];
    const float* wv    = (const float*)d_in[13];
    const float* bv    = (const float*)d_in[14];
    const float* gamma = (const float*)d_in[15];
    const float* w_out = (const float*)d_in[16];
    const float* b_out = (const float*)d_in[17];

    // workspace layout (bytes), all chunks 16B-aligned
    const size_t SZ_FR  = (size_t)BATCH*PN*CHN*4;        // 4,917,248
    const size_t SZ_FBI = (size_t)BATCH*FBST*2;          // 5,048,320
    const size_t SZ_WT  = (size_t)NBLK*2*9*CHN*CHN*2;    //   737,280
    const size_t SZ_QK  = (size_t)BATCH*NSP*C8*2;        //   294,912
    const size_t SZ_VB  = (size_t)BATCH*CHN*NSP*2;       // 2,359,296
    const size_t SZ_AT  = (size_t)BATCH*PN2*CHN*4;       // 5,537,792
    const size_t SZ_WO  = (size_t)81*CIN*CHN*4;          //    62,208
    const size_t SZ_WQ  = (size_t)80*CHN*2;              //    10,240
    char* p = (char*)d_ws;
    float* FR      = (float*)p;           p += SZ_FR;
    short* FBI0raw = (short*)p;           p += SZ_FBI;
    short* FBI1raw = (short*)p;           p += SZ_FBI;
    short* Whi     = (short*)p;           p += SZ_WT;
    short* Wlo     = (short*)p;           p += SZ_WT;
    short* Qb16    = (short*)p;           p += SZ_QK;
    short* Kb16    = (short*)p;           p += SZ_QK;
    short* Vb16    = (short*)p;           p += SZ_VB;
    float* AT      = (float*)p;           p += SZ_AT;
    float* Wo      = (float*)p;           p += SZ_WO;
    short* Wqh     = (short*)p;           p += SZ_WQ;
    short* Wql     = (short*)p;           p += SZ_WQ;
    float* Kinf    = (float*)p;           p += 32;
    short* FBI0 = FBI0raw + (size_t)GUARD*128;
    short* FBI1 = FBI1raw + (size_t)GUARD*128;
    float* outp = (float*)d_out;

    hipMemsetAsync(FR, 0, SZ_FR, stream);
    hipMemsetAsync(FBI0raw, 0, SZ_FBI, stream);
    hipMemsetAsync(FBI1raw, 0, SZ_FBI, stream);
    hipMemsetAsync(AT, 0, SZ_AT, stream);
    hipMemsetAsync(Kinf, 0, 32, stream);

    const int feat = BATCH*CHN*NSP;
    dim3 blk(256);

    k_prep_w<<<(NBLK*2*9*CHN*CHN + 255)/256, blk, 0, stream>>>(rw1, rw2, Whi, Wlo);
    k_prep_wqkv<<<(80*CHN + 255)/256, blk, 0, stream>>>(wq, wk, wv, Wqh, Wql);
    k_prep_wout<<<(81*CIN*CHN + 255)/256, blk, 0, stream>>>(w_out, Wo);
    k_conv_in<<<(feat + 255)/256, blk, 0, stream>>>(x, w_in, b_in, a_in, FR, FBI0);
    for (int i = 0; i < NBLK; ++i) {
        k_conv3_mfma<<<BATCH*294, blk, 0, stream>>>(
            FBI0,
            Whi + (size_t)(2*i)*9*CHN*CHN, Wlo + (size_t)(2*i)*9*CHN*CHN,
            rb1 + i*CHN, ra + i, (float*)nullptr, FBI1, 0);
        k_conv3_mfma<<<BATCH*294, blk, 0, stream>>>(
            FBI1,
            Whi + (size_t)(2*i+1)*9*CHN*CHN, Wlo + (size_t)(2*i+1)*9*CHN*CHN,
            rb2 + i*CHN, ra + i, FR, FBI0, 1);
    }
    k_qkv_mfma<<<BATCH*147, blk, 0, stream>>>(
        FBI0, Wqh, Wql, bq, bk, bv, Qb16, Kb16, Vb16, Kinf);
    k_attn_mfma<<<BATCH*(NSP/32), blk, 0, stream>>>(
        Qb16, Kb16, Vb16, FR, gamma, Kinf, AT);
    k_conv_out<<<(BATCH*NSP)/16, blk, 0, stream>>>(AT, Wo, b_out, outp);
}